// Round 13
// baseline (573.701 us; speedup 1.0000x reference)
//
#include <hip/hip_runtime.h>
#include <hip/hip_bf16.h>

// FeaStConv x4 on MI355X.
//  (1) (xj-xi)@u = p[src]-p[dst] with p = x@u per node (p padded to [N,8]).
//  (2) layers 1-3: aggregate-then-transform (gather x 256B/edge -> Agg ->
//      dense MFMA GEMM). Layer 4: transform-first via k_y4p, final gathers
//      y4 rows per edge.
// Round 13: (a) agg128 gather pipeline 16-deep (two 8-groups in flight);
// (b) y4 stored bf16 (stride 24) -> final_fast does 3 scattered loads/edge
// instead of 5 (36B vs 80B); (c) p6 fused into build_x0 (-1 dispatch).

#define HH 6
constexpr int NN = 50000;
constexpr int NE = 1600000;
constexpr int NBK = 196;           // buckets: dst>>8, covers 50176 nodes
constexpr int SWG = 256;           // sort workgroups
constexpr int EPW = NE / SWG;      // 6250 edges per sort wg

typedef __attribute__((ext_vector_type(8))) short bf16x8;
typedef __attribute__((ext_vector_type(4))) float f32x4;

static __device__ __forceinline__ float b2f(__hip_bfloat16 v) { return __bfloat162float(v); }
static __device__ __forceinline__ float u2f(unsigned short u) {
    return __uint_as_float(((unsigned int)u) << 16);
}
static __device__ __forceinline__ unsigned short f2bu(float v) {
    __hip_bfloat16 b = __float2bfloat16(v);
    return *reinterpret_cast<unsigned short*>(&b);
}
static __device__ __forceinline__ float lo2f(unsigned int w) {
    return __uint_as_float(w << 16);
}
static __device__ __forceinline__ float hi2f(unsigned int w) {
    return __uint_as_float(w & 0xffff0000u);
}
static __device__ __forceinline__ unsigned int pk2(float lo, float hi) {
    return ((unsigned int)f2bu(hi) << 16) | (unsigned int)f2bu(lo);
}
static __device__ __forceinline__ float ldf(const void* p, int i, int f32) {
    return f32 ? ((const float*)p)[i] : b2f(((const __hip_bfloat16*)p)[i]);
}
static __device__ __forceinline__ int ldi(const int* e32, int i, int i64) {
    return i64 ? e32[2 * i] : e32[i];
}
// async global->LDS: each lane copies 4B; lane i lands at ldst + i*4
static __device__ __forceinline__ void dma4(const void* g, void* l) {
    __builtin_amdgcn_global_load_lds(
        (const __attribute__((address_space(1))) void*)g,
        (__attribute__((address_space(3))) void*)l, 4, 0, 0);
}

// ---------------- dtype detection ----------------
__global__ void k_detect(const void* pos, const void* ei, int* flags) {
    __shared__ float smax[256];
    __shared__ int anynz;
    int t = threadIdx.x;
    if (t == 0) anynz = 0;
    const __hip_bfloat16* pb = (const __hip_bfloat16*)pos;
    float m = 0.f;
    for (int i = t; i < 2048; i += 256) {
        float v = fabsf(b2f(pb[i]));
        if (v != v) v = 1e30f;
        m = fmaxf(m, v);
    }
    smax[t] = m;
    __syncthreads();
    for (int s = 128; s > 0; s >>= 1) {
        if (t < s) smax[t] = fmaxf(smax[t], smax[t + s]);
        __syncthreads();
    }
    const int* e32 = (const int*)ei;
    if (t < 128 && e32[2 * t + 1] != 0) anynz = 1;
    __syncthreads();
    if (t == 0) {
        flags[0] = (smax[0] > 1e6f) ? 1 : 0;
        flags[1] = anynz ? 0 : 1;
    }
}

// ---------------- input assembly + layer-1 p: x0 bf16 [N,8]; p8 [N,8] -----
__global__ void k_build_x0(const void* __restrict__ pos, const void* __restrict__ nrm,
                           const void* __restrict__ u1,
                           unsigned short* __restrict__ x0b, float* __restrict__ p8,
                           const int* __restrict__ flags) {
    int f32 = flags[0];
    int i = blockIdx.x * blockDim.x + threadIdx.x;
    if (i >= NN) return;
    float xv[6];
#pragma unroll
    for (int j = 0; j < 3; j++) {
        unsigned short a = f32 ? f2bu(((const float*)pos)[i * 3 + j])
                               : ((const unsigned short*)pos)[i * 3 + j];
        unsigned short b = f32 ? f2bu(((const float*)nrm)[i * 3 + j])
                               : ((const unsigned short*)nrm)[i * 3 + j];
        x0b[i * 8 + j]     = a;
        x0b[i * 8 + 3 + j] = b;
        xv[j]     = u2f(a);
        xv[3 + j] = u2f(b);
    }
    x0b[i * 8 + 6] = 0;
    x0b[i * 8 + 7] = 0;
    float acc[HH] = {};
#pragma unroll
    for (int k = 0; k < 6; k++)
#pragma unroll
        for (int h = 0; h < HH; h++) acc[h] = fmaf(xv[k], ldf(u1, k * HH + h, f32), acc[h]);
#pragma unroll
    for (int h = 0; h < HH; h++) p8[(size_t)i * 8 + h] = acc[h];
    p8[(size_t)i * 8 + 6] = 0.f;
    p8[(size_t)i * 8 + 7] = 0.f;
}

// ---------------- CSR build: two-level counting sort ----------------
__global__ void __launch_bounds__(256) k_sortA(const int* __restrict__ ei,
                                               int* __restrict__ cntT,
                                               const int* __restrict__ flags) {
    __shared__ int hist[NBK];
    int i64 = flags[1];
    int t = threadIdx.x, w = blockIdx.x;
    for (int b = t; b < NBK; b += 256) hist[b] = 0;
    __syncthreads();
    int start = w * EPW, end = start + EPW;
    for (int e = start + t; e < end; e += 256) {
        int d = ldi(ei, NE + e, i64);
        atomicAdd(&hist[d >> 8], 1);
    }
    __syncthreads();
    for (int b = t; b < NBK; b += 256) cntT[b * SWG + w] = hist[b];
}

// -------- 3-phase exclusive scan over cntT[NBK*SWG] --------
__global__ void __launch_bounds__(256) k_scan_local(const int* __restrict__ a, int n,
                                                    int* __restrict__ o,
                                                    int* __restrict__ bsums) {
    __shared__ int ws[4];
    int b = blockIdx.x, t = threadIdx.x, lane = t & 63, wid = t >> 6;
    int idx = b * 256 + t;
    int v = (idx < n) ? a[idx] : 0;
    int incl = v;
#pragma unroll
    for (int off = 1; off < 64; off <<= 1) {
        int nb = __shfl_up(incl, off, 64);
        if (lane >= off) incl += nb;
    }
    if (lane == 63) ws[wid] = incl;
    __syncthreads();
    int wpre = 0, tot = 0;
#pragma unroll
    for (int wi = 0; wi < 4; wi++) {
        int s = ws[wi];
        if (wi < wid) wpre += s;
        tot += s;
    }
    if (idx < n) o[idx] = wpre + incl - v;
    if (t == 0) bsums[b] = tot;
}

__global__ void __launch_bounds__(256) k_scan_sums(const int* __restrict__ bsums,
                                                   int* __restrict__ bpre,
                                                   int* __restrict__ o, int n, int nb) {
    __shared__ int ws[4];
    int t = threadIdx.x, lane = t & 63, wid = t >> 6;
    int v = (t < nb) ? bsums[t] : 0;
    int incl = v;
#pragma unroll
    for (int off = 1; off < 64; off <<= 1) {
        int nbv = __shfl_up(incl, off, 64);
        if (lane >= off) incl += nbv;
    }
    if (lane == 63) ws[wid] = incl;
    __syncthreads();
    int wpre = 0, tot = 0;
#pragma unroll
    for (int wi = 0; wi < 4; wi++) {
        int s = ws[wi];
        if (wi < wid) wpre += s;
        tot += s;
    }
    if (t < nb) bpre[t] = wpre + incl - v;
    if (t == 0) o[n] = tot;
}

__global__ void __launch_bounds__(256) k_scan_add(int* __restrict__ o, int n,
                                                  const int* __restrict__ bpre) {
    int idx = blockIdx.x * 256 + threadIdx.x;
    if (idx < n) o[idx] += bpre[blockIdx.x];
}

// stage B: scatter packed {dloc,src} into per-(bucket,wg) contiguous ranges
__global__ void __launch_bounds__(256) k_sortB(const int* __restrict__ ei,
                                               const int* __restrict__ base2,
                                               unsigned int* __restrict__ ebuck,
                                               const int* __restrict__ flags) {
    __shared__ int cur[NBK];
    int i64 = flags[1];
    int t = threadIdx.x, w = blockIdx.x;
    for (int b = t; b < NBK; b += 256) cur[b] = base2[b * SWG + w];
    __syncthreads();
    int start = w * EPW, end = start + EPW;
    for (int e = start + t; e < end; e += 256) {
        int s = ldi(ei, e, i64), d = ldi(ei, NE + e, i64);
        int slot = atomicAdd(&cur[d >> 8], 1);
        ebuck[slot] = (unsigned int)s | ((unsigned int)(d & 255) << 16);
    }
}

// stage C: LDS counting sort within one bucket; writes offs + fine scatter
__global__ void __launch_bounds__(256) k_sortC(const unsigned int* __restrict__ ebuck,
                                               const int* __restrict__ base2,
                                               int* __restrict__ offs,
                                               int* __restrict__ ssrc) {
    __shared__ int cnt[256];
    __shared__ int ws[4];
    int t = threadIdx.x, b = blockIdx.x;
    int lane = t & 63, wid = t >> 6;
    cnt[t] = 0;
    __syncthreads();
    int bs = base2[b * SWG], be = base2[(b + 1) * SWG];
    for (int e = bs + t; e < be; e += 256)
        atomicAdd(&cnt[(ebuck[e] >> 16) & 255], 1);
    __syncthreads();
    int v = cnt[t];
    int incl = v;
#pragma unroll
    for (int off = 1; off < 64; off <<= 1) {
        int nb = __shfl_up(incl, off, 64);
        if (lane >= off) incl += nb;
    }
    if (lane == 63) ws[wid] = incl;
    __syncthreads();
    int wpre = 0;
#pragma unroll
    for (int wi = 0; wi < 4; wi++)
        if (wi < wid) wpre += ws[wi];
    int excl = wpre + incl - v;
    int gn = b * 256 + t;
    if (gn <= NN) offs[gn] = bs + excl;
    __syncthreads();
    cnt[t] = bs + excl;                // becomes the scatter cursor
    __syncthreads();
    for (int e = bs + t; e < be; e += 256) {
        unsigned int rec = ebuck[e];
        int slot = atomicAdd(&cnt[(rec >> 16) & 255], 1);
        ssrc[slot] = (int)(rec & 0xffffu);
    }
}

// ---------------- p = x @ u  ->  p8 [N,8] fp32 (layers 2-3) ----------------
__global__ void __launch_bounds__(256) k_compute_p128(const unsigned short* __restrict__ x,
                                                      const void* __restrict__ u,
                                                      float* __restrict__ p8,
                                                      const int* __restrict__ flags) {
    int f32 = flags[0];
    int wave = (blockIdx.x * blockDim.x + threadIdx.x) >> 6;
    int lane = threadIdx.x & 63;
    if (wave >= NN) return;
    unsigned int w = *(const unsigned int*)(x + (size_t)wave * 128 + 2 * lane);
    float x0 = lo2f(w);
    float x1 = hi2f(w);
    float acc[HH];
#pragma unroll
    for (int h = 0; h < HH; h++)
        acc[h] = x0 * ldf(u, (2 * lane) * HH + h, f32) + x1 * ldf(u, (2 * lane + 1) * HH + h, f32);
#pragma unroll
    for (int off = 32; off > 0; off >>= 1) {
#pragma unroll
        for (int h = 0; h < HH; h++) acc[h] += __shfl_down(acc[h], off, 64);
    }
    if (lane == 0) {
#pragma unroll
        for (int h = 0; h < HH; h++) p8[(size_t)wave * 8 + h] = acc[h];
    }
}

// ---------------- fused softmax + aggregation, CIN=128 ----------
// Phase A: lane=edge, fp32 q[6] -> 32B LDS entry; rowElem in reg.
// Phase B: broadcast ds_read q, coalesced dword gather with TWO 8-groups
// in flight (16-deep pipeline), 12 scalar v_fma.
__global__ void __launch_bounds__(256) k_agg128(const unsigned short* __restrict__ xb,
                                                const float* __restrict__ p8,
                                                const void* __restrict__ cvec,
                                                const int* __restrict__ ssrc,
                                                const int* __restrict__ offs,
                                                unsigned short* __restrict__ agg,
                                                const int* __restrict__ flags) {
    __shared__ float qs[4][64][8];   // 8 KB: q0..q5 + pad
    int f32 = flags[0];
    int wid = threadIdx.x >> 6, lane = threadIdx.x & 63;
    int node = (blockIdx.x * blockDim.x + threadIdx.x) >> 6;
    if (node >= NN) return;
    int s0 = offs[node], s1 = offs[node + 1];
    int deg = s1 - s0;
    float scale = 1.0f / (float)(deg > 0 ? deg : 1);
    const float* pn = p8 + (size_t)node * 8;
    float pd[HH];
#pragma unroll
    for (int h = 0; h < HH; h++) pd[h] = pn[h] - ldf(cvec, h, f32);

    float a0[HH] = {}, a1[HH] = {};
    for (int base = s0; base < s1; base += 64) {
        int cnt = (s1 - base < 64) ? (s1 - base) : 64;
        // ---- phase A: lane = edge; fp32 q -> LDS; rowElem stays in reg ----
        unsigned int rowElem = 0;
        {
            int e = base + lane;
            float q0 = 0, q1 = 0, q2 = 0, q3 = 0, q4 = 0, q5 = 0;
            if (e < s1) {
                int j = ssrc[e];
                const float* pj = p8 + (size_t)j * 8;
                float4 pa = *(const float4*)pj;
                float2 pb = *(const float2*)(pj + 4);
                float t0 = pa.x - pd[0], t1 = pa.y - pd[1], t2 = pa.z - pd[2];
                float t3 = pa.w - pd[3], t4 = pb.x - pd[4], t5 = pb.y - pd[5];
                float mx = fmaxf(fmaxf(fmaxf(t0, t1), fmaxf(t2, t3)), fmaxf(t4, t5));
                q0 = __expf(t0 - mx); q1 = __expf(t1 - mx); q2 = __expf(t2 - mx);
                q3 = __expf(t3 - mx); q4 = __expf(t4 - mx); q5 = __expf(t5 - mx);
                float inv = 1.0f / (q0 + q1 + q2 + q3 + q4 + q5);
                q0 *= inv; q1 *= inv; q2 *= inv; q3 *= inv; q4 *= inv; q5 *= inv;
                rowElem = (unsigned int)j * 128u;
            }
            float4 qa = {q0, q1, q2, q3};
            float2 qb = {q4, q5};
            *(float4*)&qs[wid][lane][0] = qa;
            *(float2*)&qs[wid][lane][4] = qb;
        }
        // ---- phase B: 16-deep pipelined gather + broadcast LDS q ----
        int cnt8 = (cnt + 7) & ~7;
        unsigned int xwA[8], xwB[8];
        auto loadg = [&](unsigned int* xw, int s) {
#pragma unroll
            for (int u = 0; u < 8; u++) {
                unsigned int ro =
                    (unsigned int)__builtin_amdgcn_readlane((int)rowElem, s + u);
                xw[u] = *(const unsigned int*)(xb + (size_t)ro + 2 * lane);
            }
        };
        auto consume = [&](const unsigned int* xw, int s) {
#pragma unroll
            for (int u = 0; u < 8; u++) {
                float4 qa = *(const float4*)&qs[wid][s + u][0];   // broadcast
                float2 qb = *(const float2*)&qs[wid][s + u][4];
                float x0v = lo2f(xw[u]);
                float x1v = hi2f(xw[u]);
                a0[0] = fmaf(qa.x, x0v, a0[0]);
                a1[0] = fmaf(qa.x, x1v, a1[0]);
                a0[1] = fmaf(qa.y, x0v, a0[1]);
                a1[1] = fmaf(qa.y, x1v, a1[1]);
                a0[2] = fmaf(qa.z, x0v, a0[2]);
                a1[2] = fmaf(qa.z, x1v, a1[2]);
                a0[3] = fmaf(qa.w, x0v, a0[3]);
                a1[3] = fmaf(qa.w, x1v, a1[3]);
                a0[4] = fmaf(qb.x, x0v, a0[4]);
                a1[4] = fmaf(qb.x, x1v, a1[4]);
                a0[5] = fmaf(qb.y, x0v, a0[5]);
                a1[5] = fmaf(qb.y, x1v, a1[5]);
            }
        };
        int s = 0;
        for (; s + 16 <= cnt8; s += 16) {
            loadg(xwA, s);
            loadg(xwB, s + 8);
            consume(xwA, s);
            consume(xwB, s + 8);
        }
        if (s < cnt8) {
            loadg(xwA, s);
            consume(xwA, s);
        }
    }
    unsigned short* ar = agg + (size_t)node * 768;
#pragma unroll
    for (int h = 0; h < HH; h++) {
        *(unsigned int*)(ar + h * 128 + 2 * lane) = pk2(a0[h] * scale, a1[h] * scale);
    }
}

// ---------------- fused softmax + aggregation, CIN=6 (DMA staged) ---------
__global__ void __launch_bounds__(256) k_agg6(const unsigned short* __restrict__ xb,
                                              const float* __restrict__ p8,
                                              const void* __restrict__ cvec,
                                              const int* __restrict__ ssrc,
                                              const int* __restrict__ offs,
                                              float* __restrict__ agg,
                                              const int* __restrict__ flags) {
    __shared__ unsigned short stage6[4][64 * 8];     // 4 KB: 64 rows x 16 B
    __shared__ float qsf[4][64][8];                  // 8 KB: q[6] + rowbyte bits
    int f32 = flags[0];
    int wid = threadIdx.x >> 6, lane = threadIdx.x & 63;
    int node = (blockIdx.x * blockDim.x + threadIdx.x) >> 6;
    if (node >= NN) return;
    int s0 = offs[node], s1 = offs[node + 1];
    int deg = s1 - s0;
    float scale = 1.0f / (float)(deg > 0 ? deg : 1);
    const float* pn = p8 + (size_t)node * 8;
    float pd[HH];
#pragma unroll
    for (int h = 0; h < HH; h++) pd[h] = pn[h] - ldf(cvec, h, f32);

    float acc6 = 0.f;
    int hh6 = lane / 6, kk6 = lane - hh6 * 6;
    const char* xbase = (const char*)xb;
    for (int base = s0; base < s1; base += 64) {
        int cnt = (s1 - base < 64) ? (s1 - base) : 64;
        {
            int e = base + lane;
            float q0 = 0, q1 = 0, q2 = 0, q3 = 0, q4 = 0, q5 = 0;
            unsigned int rowByte = 0;
            if (e < s1) {
                int j = ssrc[e];
                const float* pj = p8 + (size_t)j * 8;
                float4 pa = *(const float4*)pj;
                float2 pb = *(const float2*)(pj + 4);
                float t0 = pa.x - pd[0], t1 = pa.y - pd[1], t2 = pa.z - pd[2];
                float t3 = pa.w - pd[3], t4 = pb.x - pd[4], t5 = pb.y - pd[5];
                float mx = fmaxf(fmaxf(fmaxf(t0, t1), fmaxf(t2, t3)), fmaxf(t4, t5));
                q0 = __expf(t0 - mx); q1 = __expf(t1 - mx); q2 = __expf(t2 - mx);
                q3 = __expf(t3 - mx); q4 = __expf(t4 - mx); q5 = __expf(t5 - mx);
                float inv = 1.0f / (q0 + q1 + q2 + q3 + q4 + q5);
                q0 *= inv; q1 *= inv; q2 *= inv; q3 *= inv; q4 *= inv; q5 *= inv;
                rowByte = (unsigned int)j * 16u;
            }
            float4 qa = {q0, q1, q2, q3};
            float4 qb = {q4, q5, __uint_as_float(rowByte), 0.f};
            *(float4*)&qsf[wid][lane][0] = qa;
            *(float4*)&qsf[wid][lane][4] = qb;
        }
        __builtin_amdgcn_sched_barrier(0);
#pragma unroll
        for (int t = 0; t < 4; t++) {
            int r = t * 16 + (lane >> 2);
            unsigned int rb = __float_as_uint(qsf[wid][r][6]);
            dma4(xbase + rb + (lane & 3) * 4, &stage6[wid][t * 128]);
        }
        __builtin_amdgcn_s_waitcnt(0x0f70);          // vmcnt(0) only
        __builtin_amdgcn_sched_barrier(0);
        if (lane < 36) {
            for (int s = 0; s < cnt; s++) {
                float qh = qsf[wid][s][hh6];
                float xv = u2f(stage6[wid][s * 8 + kk6]);
                acc6 = fmaf(qh, xv, acc6);
            }
        }
        __builtin_amdgcn_sched_barrier(0);
    }
    if (lane < 36) agg[(size_t)node * 36 + lane] = acc6 * scale;
}

// ---------------- fused weight repacks ----------------
__global__ void k_repack_all(const void* __restrict__ W1, const void* __restrict__ W2,
                             const void* __restrict__ W3, const void* __restrict__ W4,
                             const void* __restrict__ U4,
                             float* __restrict__ wstk1, unsigned short* __restrict__ wt2,
                             unsigned short* __restrict__ wt3, unsigned short* __restrict__ wt4,
                             unsigned short* __restrict__ u4,
                             const int* __restrict__ flags) {
    int f32 = flags[0];
    int idx = blockIdx.x * blockDim.x + threadIdx.x;
    if (idx < 4608) {
        int f = idx & 127, m = idx >> 7;
        int h = m / 6, k = m - h * 6;
        wstk1[idx] = ldf(W1, k * 768 + h * 128 + f, f32);
        return;
    }
    idx -= 4608;
    if (idx < 98304) {
        int f = idx / 768, m = idx % 768;
        int h = m >> 7, kk = m & 127;
        wt2[idx] = f2bu(ldf(W2, kk * 768 + h * 128 + f, f32));
        return;
    }
    idx -= 98304;
    if (idx < 98304) {
        int f = idx / 768, m = idx % 768;
        int h = m >> 7, kk = m & 127;
        wt3[idx] = f2bu(ldf(W3, kk * 768 + h * 128 + f, f32));
        return;
    }
    idx -= 98304;
    if (idx < 4096) {
        int n = idx >> 7, k = idx & 127;
        wt4[idx] = (n < 18) ? f2bu(ldf(W4, k * 18 + n, f32)) : (unsigned short)0;
        return;
    }
    idx -= 4096;
    if (idx < 2048) {
        int n = idx >> 7, k = idx & 127;
        u4[idx] = (n < 6) ? f2bu(ldf(U4, k * 6 + n, f32)) : (unsigned short)0;
    }
}

// ---------------- layer-1 GEMM (fp32, K=36), writes bf16 x ----------------
__global__ void __launch_bounds__(256) k_gemm_f32(const float* __restrict__ A,
                                                  const float* __restrict__ B,
                                                  const void* __restrict__ bias,
                                                  unsigned short* __restrict__ C,
                                                  int M, int K, int relu,
                                                  const int* __restrict__ flags) {
    int f32 = flags[0];
    __shared__ float As[16][68];
    __shared__ float Bs[16][128];
    int tid = threadIdx.x;
    int tx = tid & 15;
    int ty = tid >> 4;
    int bm = blockIdx.x * 64;
    int arow = tid >> 2, ak = (tid & 3) * 4;
    int brow = tid >> 4, bcol = (tid & 15) * 8;
    float acc[4][8] = {};
    for (int k0 = 0; k0 < K; k0 += 16) {
        float4 av = {0, 0, 0, 0};
        int gr = bm + arow;
        if (gr < M && (k0 + ak) < K) av = *(const float4*)(A + (size_t)gr * K + k0 + ak);
        As[ak + 0][arow] = av.x;
        As[ak + 1][arow] = av.y;
        As[ak + 2][arow] = av.z;
        As[ak + 3][arow] = av.w;
        float4 bv0 = {0, 0, 0, 0}, bv1 = {0, 0, 0, 0};
        if ((k0 + brow) < K) {
            const float* bp = B + (size_t)(k0 + brow) * 128 + bcol;
            bv0 = *(const float4*)bp;
            bv1 = *(const float4*)(bp + 4);
        }
        *(float4*)&Bs[brow][bcol]     = bv0;
        *(float4*)&Bs[brow][bcol + 4] = bv1;
        __syncthreads();
#pragma unroll
        for (int kk = 0; kk < 16; kk++) {
            float a_[4], b_[8];
#pragma unroll
            for (int j = 0; j < 4; j++) a_[j] = As[kk][ty * 4 + j];
#pragma unroll
            for (int j = 0; j < 8; j++) b_[j] = Bs[kk][tx * 8 + j];
#pragma unroll
            for (int i = 0; i < 4; i++)
#pragma unroll
                for (int j = 0; j < 8; j++) acc[i][j] = fmaf(a_[i], b_[j], acc[i][j]);
        }
        __syncthreads();
    }
#pragma unroll
    for (int i = 0; i < 4; i++) {
        int row = bm + ty * 4 + i;
        if (row >= M) continue;
#pragma unroll
        for (int j = 0; j < 8; j++) {
            int col = tx * 8 + j;
            float v = acc[i][j] + ldf(bias, col, f32);
            if (relu) v = fmaxf(v, 0.f);
            C[(size_t)row * 128 + col] = f2bu(v);
        }
    }
}

// ---------------- MFMA GEMM: C[M,128] = A[M,768]bf16 @ Wt^T + bias, ReLU ----
__global__ void __launch_bounds__(256) k_gemm_mfma(const unsigned short* __restrict__ A,
                                                   const unsigned short* __restrict__ Bt,
                                                   const void* __restrict__ bias,
                                                   unsigned short* __restrict__ C,
                                                   int M, int relu,
                                                   const int* __restrict__ flags) {
    constexpr int K = 768, BK = 64;
    __shared__ unsigned short As[64][72];
    __shared__ unsigned short Bs[128][72];
    int f32 = flags[0];
    int tid = threadIdx.x;
    int lane = tid & 63, wid = tid >> 6;
    int wm = wid & 1, wn = wid >> 1;
    int bm = blockIdx.x * 64;
    int l15 = lane & 15, lq = lane >> 4;
    f32x4 acc[2][4] = {};

    for (int k0 = 0; k0 < K; k0 += BK) {
#pragma unroll
        for (int cc = 0; cc < 2; cc++) {
            int c = tid + cc * 256;
            int r = c >> 3, kc = (c & 7) * 8;
            bf16x8 av = {};
            int gr = bm + r;
            if (gr < M) av = *(const bf16x8*)(A + (size_t)gr * K + k0 + kc);
            *(bf16x8*)&As[r][kc] = av;
        }
#pragma unroll
        for (int cc = 0; cc < 4; cc++) {
            int c = tid + cc * 256;
            int n = c >> 3, kc = (c & 7) * 8;
            *(bf16x8*)&Bs[n][kc] = *(const bf16x8*)(Bt + (size_t)n * K + k0 + kc);
        }
        __syncthreads();
#pragma unroll
        for (int ks = 0; ks < BK; ks += 32) {
            int koff = ks + lq * 8;
            bf16x8 af[2], bfr[4];
#pragma unroll
            for (int tm = 0; tm < 2; tm++)
                af[tm] = *(const bf16x8*)&As[wm * 32 + tm * 16 + l15][koff];
#pragma unroll
            for (int tn = 0; tn < 4; tn++)
                bfr[tn] = *(const bf16x8*)&Bs[wn * 64 + tn * 16 + l15][koff];
#pragma unroll
            for (int tm = 0; tm < 2; tm++)
#pragma unroll
                for (int tn = 0; tn < 4; tn++)
                    acc[tm][tn] = __builtin_amdgcn_mfma_f32_16x16x32_bf16(
                        af[tm], bfr[tn], acc[tm][tn], 0, 0, 0);
        }
        __syncthreads();
    }
#pragma unroll
    for (int tm = 0; tm < 2; tm++) {
#pragma unroll
        for (int tn = 0; tn < 4; tn++) {
            int col = wn * 64 + tn * 16 + l15;
            float bv = ldf(bias, col, f32);
#pragma unroll
            for (int r = 0; r < 4; r++) {
                int row = bm + wm * 32 + tm * 16 + lq * 4 + r;
                if (row < M) {
                    float v = acc[tm][tn][r] + bv;
                    if (relu) v = fmaxf(v, 0.f);
                    C[(size_t)row * 128 + col] = f2bu(v);
                }
            }
        }
    }
}

// ---------------- layer-4: y4 = x@W4 (bf16 out) AND p = x@u ---------------
__global__ void __launch_bounds__(256) k_y4p(const unsigned short* __restrict__ xb,
                                             const unsigned short* __restrict__ wt4,
                                             const unsigned short* __restrict__ u4,
                                             unsigned short* __restrict__ y4h,
                                             float* __restrict__ p8) {
    int tid = threadIdx.x;
    int lane = tid & 63, wid = tid >> 6;
    int l15 = lane & 15, lq = lane >> 4;
    int bm = blockIdx.x * 64 + wid * 16;
    f32x4 acc[2] = {};
    f32x4 accp = {};
#pragma unroll
    for (int ks = 0; ks < 128; ks += 32) {
        int koff = ks + lq * 8;
        bf16x8 af = {};
        int row = bm + l15;
        if (row < NN) af = *(const bf16x8*)(xb + (size_t)row * 128 + koff);
        bf16x8 b0 = *(const bf16x8*)(wt4 + (0 * 16 + l15) * 128 + koff);
        bf16x8 b1 = *(const bf16x8*)(wt4 + (1 * 16 + l15) * 128 + koff);
        bf16x8 bu = *(const bf16x8*)(u4 + l15 * 128 + koff);
        acc[0] = __builtin_amdgcn_mfma_f32_16x16x32_bf16(af, b0, acc[0], 0, 0, 0);
        acc[1] = __builtin_amdgcn_mfma_f32_16x16x32_bf16(af, b1, acc[1], 0, 0, 0);
        accp = __builtin_amdgcn_mfma_f32_16x16x32_bf16(af, bu, accp, 0, 0, 0);
    }
#pragma unroll
    for (int t = 0; t < 2; t++) {
#pragma unroll
        for (int r = 0; r < 4; r++) {
            int row = bm + lq * 4 + r;
            int col = t * 16 + l15;
            if (row < NN && col < 18) y4h[(size_t)row * 24 + col] = f2bu(acc[t][r]);
        }
    }
#pragma unroll
    for (int r = 0; r < 4; r++) {
        int row = bm + lq * 4 + r;
        if (row < NN && l15 < 6) p8[(size_t)row * 8 + l15] = accp[r];
    }
}

// ---------------- final layer: lane-per-edge over bf16 y4 -----------------
__global__ void __launch_bounds__(256) k_final_fast(const unsigned short* __restrict__ y4h,
                                                    const float* __restrict__ p8,
                                                    const void* __restrict__ cvec,
                                                    const int* __restrict__ ssrc,
                                                    const int* __restrict__ offs,
                                                    const void* __restrict__ bias,
                                                    void* __restrict__ out,
                                                    const int* __restrict__ flags) {
    int f32 = flags[0];
    int lane = threadIdx.x & 63;
    int node = (blockIdx.x * blockDim.x + threadIdx.x) >> 6;
    if (node >= NN) return;
    int s0 = offs[node], s1 = offs[node + 1];
    int deg = s1 - s0;
    float scale = 1.0f / (float)(deg > 0 ? deg : 1);
    const float* pn = p8 + (size_t)node * 8;
    float pd[HH];
#pragma unroll
    for (int h = 0; h < HH; h++) pd[h] = pn[h] - ldf(cvec, h, f32);

    float f0 = 0, f1 = 0, f2 = 0;
    for (int base = s0; base < s1; base += 64) {
        int e = base + lane;
        if (e < s1) {
            int j = ssrc[e];
            const float* pj = p8 + (size_t)j * 8;
            float4 pa = *(const float4*)pj;
            float2 pb = *(const float2*)(pj + 4);
            float t0 = pa.x - pd[0], t1 = pa.y - pd[1], t2 = pa.z - pd[2];
            float t3 = pa.w - pd[3], t4 = pb.x - pd[4], t5 = pb.y - pd[5];
            float mx = fmaxf(fmaxf(fmaxf(t0, t1), fmaxf(t2, t3)), fmaxf(t4, t5));
            float q0 = __expf(t0 - mx), q1 = __expf(t1 - mx), q2 = __expf(t2 - mx);
            float q3 = __expf(t3 - mx), q4 = __expf(t4 - mx), q5 = __expf(t5 - mx);
            float inv = 1.0f / (q0 + q1 + q2 + q3 + q4 + q5);
            float qa[6] = {q0 * inv, q1 * inv, q2 * inv, q3 * inv, q4 * inv, q5 * inv};
            const unsigned int* yr = (const unsigned int*)(y4h + (size_t)j * 24);
            uint4 ua = *(const uint4*)yr;
            uint4 ub = *(const uint4*)(yr + 4);
            unsigned int uc = yr[8];
            unsigned int d[9] = {ua.x, ua.y, ua.z, ua.w, ub.x, ub.y, ub.z, ub.w, uc};
            float yv[18];
#pragma unroll
            for (int c = 0; c < 18; c++)
                yv[c] = (c & 1) ? hi2f(d[c >> 1]) : lo2f(d[c >> 1]);
#pragma unroll
            for (int h = 0; h < HH; h++) {
                f0 = fmaf(qa[h], yv[3 * h + 0], f0);
                f1 = fmaf(qa[h], yv[3 * h + 1], f1);
                f2 = fmaf(qa[h], yv[3 * h + 2], f2);
            }
        }
    }
#pragma unroll
    for (int off = 32; off > 0; off >>= 1) {
        f0 += __shfl_down(f0, off, 64);
        f1 += __shfl_down(f1, off, 64);
        f2 += __shfl_down(f2, off, 64);
    }
    if (lane == 0) {
        float r0 = f0 * scale + ldf(bias, 0, f32);
        float r1 = f1 * scale + ldf(bias, 1, f32);
        float r2 = f2 * scale + ldf(bias, 2, f32);
        if (f32) {
            float* o = (float*)out;
            o[(size_t)node * 3 + 0] = r0;
            o[(size_t)node * 3 + 1] = r1;
            o[(size_t)node * 3 + 2] = r2;
        } else {
            __hip_bfloat16* o = (__hip_bfloat16*)out;
            o[(size_t)node * 3 + 0] = __float2bfloat16(r0);
            o[(size_t)node * 3 + 1] = __float2bfloat16(r1);
            o[(size_t)node * 3 + 2] = __float2bfloat16(r2);
        }
    }
}

extern "C" void kernel_launch(void* const* d_in, const int* in_sizes, int n_in,
                              void* d_out, int out_size, void* d_ws, size_t ws_size,
                              hipStream_t stream) {
    (void)in_sizes; (void)n_in; (void)out_size; (void)ws_size;
    const void* pos = d_in[0];
    const void* nrm = d_in[1];
    const int* ei = (const int*)d_in[2];
    const void* W[4] = {d_in[3], d_in[7], d_in[11], d_in[15]};
    const void* U[4] = {d_in[4], d_in[8], d_in[12], d_in[16]};
    const void* Cc[4] = {d_in[5], d_in[9], d_in[13], d_in[17]};
    const void* Bb[4] = {d_in[6], d_in[10], d_in[14], d_in[18]};

    char* wp = (char*)d_ws;
    auto alloc = [&](size_t b) { void* r = (void*)wp; wp += (b + 255) & ~(size_t)255; return r; };
    unsigned short* xA  = (unsigned short*)alloc((size_t)NN * 128 * 2);
    unsigned short* xB  = (unsigned short*)alloc((size_t)NN * 128 * 2);
    unsigned short* x0b = (unsigned short*)alloc((size_t)NN * 8 * 2);
    float* p8     = (float*)alloc((size_t)NN * 8 * 4);
    unsigned short* y4h = (unsigned short*)alloc((size_t)NN * 24 * 2);
    int*   offs   = (int*)alloc((size_t)(NN + 1) * 4);
    int*   cntT   = (int*)alloc((size_t)NBK * SWG * 4);
    int*   base2  = (int*)alloc((size_t)(NBK * SWG + 1) * 4);
    int*   bsums  = (int*)alloc((size_t)256 * 4);
    int*   bpre   = (int*)alloc((size_t)256 * 4);
    int*   flags  = (int*)alloc(256);
    int*   ssrc   = (int*)alloc((size_t)NE * 4);
    unsigned int* ebuck = (unsigned int*)alloc((size_t)NE * 4);
    void*  aggv   = alloc((size_t)NN * 768 * 2);
    float* wstk1  = (float*)alloc((size_t)36 * 128 * 4);
    unsigned short* wt2 = (unsigned short*)alloc((size_t)128 * 768 * 2);
    unsigned short* wt3 = (unsigned short*)alloc((size_t)128 * 768 * 2);
    unsigned short* wt4 = (unsigned short*)alloc((size_t)32 * 128 * 2);
    unsigned short* u4  = (unsigned short*)alloc((size_t)16 * 128 * 2);
    unsigned short* agg_h = (unsigned short*)aggv;
    float* agg_f = (float*)aggv;

    const int NB = (NN + 255) / 256;
    const int NWB = (NN * 64 + 255) / 256;      // 256-thread wave-per-node grids
    const int GB = (NN + 63) / 64;
    const int NSC = NBK * SWG;                   // 50176

    k_detect<<<1, 256, 0, stream>>>(pos, ei, flags);
    k_sortA<<<SWG, 256, 0, stream>>>(ei, cntT, flags);
    k_scan_local<<<NBK, 256, 0, stream>>>(cntT, NSC, base2, bsums);
    k_scan_sums<<<1, 256, 0, stream>>>(bsums, bpre, base2, NSC, NBK);
    k_scan_add<<<NBK, 256, 0, stream>>>(base2, NSC, bpre);
    k_sortB<<<SWG, 256, 0, stream>>>(ei, base2, ebuck, flags);
    k_sortC<<<NBK, 256, 0, stream>>>(ebuck, base2, offs, ssrc);
    k_build_x0<<<NB, 256, 0, stream>>>(pos, nrm, U[0], x0b, p8, flags);
    k_repack_all<<<(207360 + 255) / 256, 256, 0, stream>>>(W[0], W[1], W[2], W[3], U[3],
                                                           wstk1, wt2, wt3, wt4, u4, flags);

    // ---- layer 1: 6 -> 128, relu (p fused into build_x0) ----
    k_agg6<<<NWB, 256, 0, stream>>>(x0b, p8, Cc[0], ssrc, offs, agg_f, flags);
    k_gemm_f32<<<GB, 256, 0, stream>>>(agg_f, wstk1, Bb[0], xA, NN, 36, 1, flags);

    // ---- layer 2: 128 -> 128, relu ----
    k_compute_p128<<<NWB, 256, 0, stream>>>(xA, U[1], p8, flags);
    k_agg128<<<NWB, 256, 0, stream>>>(xA, p8, Cc[1], ssrc, offs, agg_h, flags);
    k_gemm_mfma<<<GB, 256, 0, stream>>>(agg_h, wt2, Bb[1], xB, NN, 1, flags);

    // ---- layer 3: 128 -> 128, relu ----
    k_compute_p128<<<NWB, 256, 0, stream>>>(xB, U[2], p8, flags);
    k_agg128<<<NWB, 256, 0, stream>>>(xB, p8, Cc[2], ssrc, offs, agg_h, flags);
    k_gemm_mfma<<<GB, 256, 0, stream>>>(agg_h, wt3, Bb[2], xA, NN, 1, flags);

    // ---- layer 4: 128 -> 3 (transform-first; y4 bf16 + p fused) ----
    k_y4p<<<GB, 256, 0, stream>>>(xA, wt4, u4, y4h, p8);
    k_final_fast<<<NWB, 256, 0, stream>>>(y4h, p8, Cc[3], ssrc, offs, Bb[3], d_out, flags);
}

// Round 14
// 544.686 us; speedup vs baseline: 1.0533x; 1.0533x over previous
//
#include <hip/hip_runtime.h>
#include <hip/hip_bf16.h>

// FeaStConv x4 on MI355X.
//  (1) (xj-xi)@u = p[src]-p[dst] with p = x@u per node (p padded to [N,8]).
//  (2) layers 1-3: aggregate-then-transform (gather x 256B/edge -> Agg ->
//      dense MFMA GEMM). Layer 4: transform-first via k_y4p, final gathers
//      bf16 y4 rows (36B/edge).
// Round 14: REVERT r13's 16-deep agg128 pipeline (VGPR 48->52 cost a wave
// slot: occupancy 46->35%, dur 74->90 us — TLP loss > ILP gain). Back to
// r12's 8-deep phase B. Keep r13's y4-bf16 + p6-into-build_x0 (those saved
// ~21 us).

#define HH 6
constexpr int NN = 50000;
constexpr int NE = 1600000;
constexpr int NBK = 196;           // buckets: dst>>8, covers 50176 nodes
constexpr int SWG = 256;           // sort workgroups
constexpr int EPW = NE / SWG;      // 6250 edges per sort wg

typedef __attribute__((ext_vector_type(8))) short bf16x8;
typedef __attribute__((ext_vector_type(4))) float f32x4;

static __device__ __forceinline__ float b2f(__hip_bfloat16 v) { return __bfloat162float(v); }
static __device__ __forceinline__ float u2f(unsigned short u) {
    return __uint_as_float(((unsigned int)u) << 16);
}
static __device__ __forceinline__ unsigned short f2bu(float v) {
    __hip_bfloat16 b = __float2bfloat16(v);
    return *reinterpret_cast<unsigned short*>(&b);
}
static __device__ __forceinline__ float lo2f(unsigned int w) {
    return __uint_as_float(w << 16);
}
static __device__ __forceinline__ float hi2f(unsigned int w) {
    return __uint_as_float(w & 0xffff0000u);
}
static __device__ __forceinline__ unsigned int pk2(float lo, float hi) {
    return ((unsigned int)f2bu(hi) << 16) | (unsigned int)f2bu(lo);
}
static __device__ __forceinline__ float ldf(const void* p, int i, int f32) {
    return f32 ? ((const float*)p)[i] : b2f(((const __hip_bfloat16*)p)[i]);
}
static __device__ __forceinline__ int ldi(const int* e32, int i, int i64) {
    return i64 ? e32[2 * i] : e32[i];
}
// async global->LDS: each lane copies 4B; lane i lands at ldst + i*4
static __device__ __forceinline__ void dma4(const void* g, void* l) {
    __builtin_amdgcn_global_load_lds(
        (const __attribute__((address_space(1))) void*)g,
        (__attribute__((address_space(3))) void*)l, 4, 0, 0);
}

// ---------------- dtype detection ----------------
__global__ void k_detect(const void* pos, const void* ei, int* flags) {
    __shared__ float smax[256];
    __shared__ int anynz;
    int t = threadIdx.x;
    if (t == 0) anynz = 0;
    const __hip_bfloat16* pb = (const __hip_bfloat16*)pos;
    float m = 0.f;
    for (int i = t; i < 2048; i += 256) {
        float v = fabsf(b2f(pb[i]));
        if (v != v) v = 1e30f;
        m = fmaxf(m, v);
    }
    smax[t] = m;
    __syncthreads();
    for (int s = 128; s > 0; s >>= 1) {
        if (t < s) smax[t] = fmaxf(smax[t], smax[t + s]);
        __syncthreads();
    }
    const int* e32 = (const int*)ei;
    if (t < 128 && e32[2 * t + 1] != 0) anynz = 1;
    __syncthreads();
    if (t == 0) {
        flags[0] = (smax[0] > 1e6f) ? 1 : 0;
        flags[1] = anynz ? 0 : 1;
    }
}

// ---------------- input assembly + layer-1 p: x0 bf16 [N,8]; p8 [N,8] -----
__global__ void k_build_x0(const void* __restrict__ pos, const void* __restrict__ nrm,
                           const void* __restrict__ u1,
                           unsigned short* __restrict__ x0b, float* __restrict__ p8,
                           const int* __restrict__ flags) {
    int f32 = flags[0];
    int i = blockIdx.x * blockDim.x + threadIdx.x;
    if (i >= NN) return;
    float xv[6];
#pragma unroll
    for (int j = 0; j < 3; j++) {
        unsigned short a = f32 ? f2bu(((const float*)pos)[i * 3 + j])
                               : ((const unsigned short*)pos)[i * 3 + j];
        unsigned short b = f32 ? f2bu(((const float*)nrm)[i * 3 + j])
                               : ((const unsigned short*)nrm)[i * 3 + j];
        x0b[i * 8 + j]     = a;
        x0b[i * 8 + 3 + j] = b;
        xv[j]     = u2f(a);
        xv[3 + j] = u2f(b);
    }
    x0b[i * 8 + 6] = 0;
    x0b[i * 8 + 7] = 0;
    float acc[HH] = {};
#pragma unroll
    for (int k = 0; k < 6; k++)
#pragma unroll
        for (int h = 0; h < HH; h++) acc[h] = fmaf(xv[k], ldf(u1, k * HH + h, f32), acc[h]);
#pragma unroll
    for (int h = 0; h < HH; h++) p8[(size_t)i * 8 + h] = acc[h];
    p8[(size_t)i * 8 + 6] = 0.f;
    p8[(size_t)i * 8 + 7] = 0.f;
}

// ---------------- CSR build: two-level counting sort ----------------
__global__ void __launch_bounds__(256) k_sortA(const int* __restrict__ ei,
                                               int* __restrict__ cntT,
                                               const int* __restrict__ flags) {
    __shared__ int hist[NBK];
    int i64 = flags[1];
    int t = threadIdx.x, w = blockIdx.x;
    for (int b = t; b < NBK; b += 256) hist[b] = 0;
    __syncthreads();
    int start = w * EPW, end = start + EPW;
    for (int e = start + t; e < end; e += 256) {
        int d = ldi(ei, NE + e, i64);
        atomicAdd(&hist[d >> 8], 1);
    }
    __syncthreads();
    for (int b = t; b < NBK; b += 256) cntT[b * SWG + w] = hist[b];
}

// -------- 3-phase exclusive scan over cntT[NBK*SWG] --------
__global__ void __launch_bounds__(256) k_scan_local(const int* __restrict__ a, int n,
                                                    int* __restrict__ o,
                                                    int* __restrict__ bsums) {
    __shared__ int ws[4];
    int b = blockIdx.x, t = threadIdx.x, lane = t & 63, wid = t >> 6;
    int idx = b * 256 + t;
    int v = (idx < n) ? a[idx] : 0;
    int incl = v;
#pragma unroll
    for (int off = 1; off < 64; off <<= 1) {
        int nb = __shfl_up(incl, off, 64);
        if (lane >= off) incl += nb;
    }
    if (lane == 63) ws[wid] = incl;
    __syncthreads();
    int wpre = 0, tot = 0;
#pragma unroll
    for (int wi = 0; wi < 4; wi++) {
        int s = ws[wi];
        if (wi < wid) wpre += s;
        tot += s;
    }
    if (idx < n) o[idx] = wpre + incl - v;
    if (t == 0) bsums[b] = tot;
}

__global__ void __launch_bounds__(256) k_scan_sums(const int* __restrict__ bsums,
                                                   int* __restrict__ bpre,
                                                   int* __restrict__ o, int n, int nb) {
    __shared__ int ws[4];
    int t = threadIdx.x, lane = t & 63, wid = t >> 6;
    int v = (t < nb) ? bsums[t] : 0;
    int incl = v;
#pragma unroll
    for (int off = 1; off < 64; off <<= 1) {
        int nbv = __shfl_up(incl, off, 64);
        if (lane >= off) incl += nbv;
    }
    if (lane == 63) ws[wid] = incl;
    __syncthreads();
    int wpre = 0, tot = 0;
#pragma unroll
    for (int wi = 0; wi < 4; wi++) {
        int s = ws[wi];
        if (wi < wid) wpre += s;
        tot += s;
    }
    if (t < nb) bpre[t] = wpre + incl - v;
    if (t == 0) o[n] = tot;
}

__global__ void __launch_bounds__(256) k_scan_add(int* __restrict__ o, int n,
                                                  const int* __restrict__ bpre) {
    int idx = blockIdx.x * 256 + threadIdx.x;
    if (idx < n) o[idx] += bpre[blockIdx.x];
}

// stage B: scatter packed {dloc,src} into per-(bucket,wg) contiguous ranges
__global__ void __launch_bounds__(256) k_sortB(const int* __restrict__ ei,
                                               const int* __restrict__ base2,
                                               unsigned int* __restrict__ ebuck,
                                               const int* __restrict__ flags) {
    __shared__ int cur[NBK];
    int i64 = flags[1];
    int t = threadIdx.x, w = blockIdx.x;
    for (int b = t; b < NBK; b += 256) cur[b] = base2[b * SWG + w];
    __syncthreads();
    int start = w * EPW, end = start + EPW;
    for (int e = start + t; e < end; e += 256) {
        int s = ldi(ei, e, i64), d = ldi(ei, NE + e, i64);
        int slot = atomicAdd(&cur[d >> 8], 1);
        ebuck[slot] = (unsigned int)s | ((unsigned int)(d & 255) << 16);
    }
}

// stage C: LDS counting sort within one bucket; writes offs + fine scatter
__global__ void __launch_bounds__(256) k_sortC(const unsigned int* __restrict__ ebuck,
                                               const int* __restrict__ base2,
                                               int* __restrict__ offs,
                                               int* __restrict__ ssrc) {
    __shared__ int cnt[256];
    __shared__ int ws[4];
    int t = threadIdx.x, b = blockIdx.x;
    int lane = t & 63, wid = t >> 6;
    cnt[t] = 0;
    __syncthreads();
    int bs = base2[b * SWG], be = base2[(b + 1) * SWG];
    for (int e = bs + t; e < be; e += 256)
        atomicAdd(&cnt[(ebuck[e] >> 16) & 255], 1);
    __syncthreads();
    int v = cnt[t];
    int incl = v;
#pragma unroll
    for (int off = 1; off < 64; off <<= 1) {
        int nb = __shfl_up(incl, off, 64);
        if (lane >= off) incl += nb;
    }
    if (lane == 63) ws[wid] = incl;
    __syncthreads();
    int wpre = 0;
#pragma unroll
    for (int wi = 0; wi < 4; wi++)
        if (wi < wid) wpre += ws[wi];
    int excl = wpre + incl - v;
    int gn = b * 256 + t;
    if (gn <= NN) offs[gn] = bs + excl;
    __syncthreads();
    cnt[t] = bs + excl;                // becomes the scatter cursor
    __syncthreads();
    for (int e = bs + t; e < be; e += 256) {
        unsigned int rec = ebuck[e];
        int slot = atomicAdd(&cnt[(rec >> 16) & 255], 1);
        ssrc[slot] = (int)(rec & 0xffffu);
    }
}

// ---------------- p = x @ u  ->  p8 [N,8] fp32 (layers 2-3) ----------------
__global__ void __launch_bounds__(256) k_compute_p128(const unsigned short* __restrict__ x,
                                                      const void* __restrict__ u,
                                                      float* __restrict__ p8,
                                                      const int* __restrict__ flags) {
    int f32 = flags[0];
    int wave = (blockIdx.x * blockDim.x + threadIdx.x) >> 6;
    int lane = threadIdx.x & 63;
    if (wave >= NN) return;
    unsigned int w = *(const unsigned int*)(x + (size_t)wave * 128 + 2 * lane);
    float x0 = lo2f(w);
    float x1 = hi2f(w);
    float acc[HH];
#pragma unroll
    for (int h = 0; h < HH; h++)
        acc[h] = x0 * ldf(u, (2 * lane) * HH + h, f32) + x1 * ldf(u, (2 * lane + 1) * HH + h, f32);
#pragma unroll
    for (int off = 32; off > 0; off >>= 1) {
#pragma unroll
        for (int h = 0; h < HH; h++) acc[h] += __shfl_down(acc[h], off, 64);
    }
    if (lane == 0) {
#pragma unroll
        for (int h = 0; h < HH; h++) p8[(size_t)wave * 8 + h] = acc[h];
    }
}

// ---------------- fused softmax + aggregation, CIN=128 (r12 structure) ----
// Phase A: lane=edge, fp32 q[6] -> 32B LDS entry; rowElem in reg.
// Phase B: broadcast ds_read q, coalesced dword gather 8-deep, 12 v_fma.
__global__ void __launch_bounds__(256) k_agg128(const unsigned short* __restrict__ xb,
                                                const float* __restrict__ p8,
                                                const void* __restrict__ cvec,
                                                const int* __restrict__ ssrc,
                                                const int* __restrict__ offs,
                                                unsigned short* __restrict__ agg,
                                                const int* __restrict__ flags) {
    __shared__ float qs[4][64][8];   // 8 KB: q0..q5 + pad
    int f32 = flags[0];
    int wid = threadIdx.x >> 6, lane = threadIdx.x & 63;
    int node = (blockIdx.x * blockDim.x + threadIdx.x) >> 6;
    if (node >= NN) return;
    int s0 = offs[node], s1 = offs[node + 1];
    int deg = s1 - s0;
    float scale = 1.0f / (float)(deg > 0 ? deg : 1);
    const float* pn = p8 + (size_t)node * 8;
    float pd[HH];
#pragma unroll
    for (int h = 0; h < HH; h++) pd[h] = pn[h] - ldf(cvec, h, f32);

    float a0[HH] = {}, a1[HH] = {};
    for (int base = s0; base < s1; base += 64) {
        int cnt = (s1 - base < 64) ? (s1 - base) : 64;
        // ---- phase A: lane = edge; fp32 q -> LDS; rowElem stays in reg ----
        unsigned int rowElem = 0;
        {
            int e = base + lane;
            float q0 = 0, q1 = 0, q2 = 0, q3 = 0, q4 = 0, q5 = 0;
            if (e < s1) {
                int j = ssrc[e];
                const float* pj = p8 + (size_t)j * 8;
                float4 pa = *(const float4*)pj;
                float2 pb = *(const float2*)(pj + 4);
                float t0 = pa.x - pd[0], t1 = pa.y - pd[1], t2 = pa.z - pd[2];
                float t3 = pa.w - pd[3], t4 = pb.x - pd[4], t5 = pb.y - pd[5];
                float mx = fmaxf(fmaxf(fmaxf(t0, t1), fmaxf(t2, t3)), fmaxf(t4, t5));
                q0 = __expf(t0 - mx); q1 = __expf(t1 - mx); q2 = __expf(t2 - mx);
                q3 = __expf(t3 - mx); q4 = __expf(t4 - mx); q5 = __expf(t5 - mx);
                float inv = 1.0f / (q0 + q1 + q2 + q3 + q4 + q5);
                q0 *= inv; q1 *= inv; q2 *= inv; q3 *= inv; q4 *= inv; q5 *= inv;
                rowElem = (unsigned int)j * 128u;
            }
            float4 qa = {q0, q1, q2, q3};
            float2 qb = {q4, q5};
            *(float4*)&qs[wid][lane][0] = qa;
            *(float2*)&qs[wid][lane][4] = qb;
        }
        // ---- phase B: broadcast LDS q + coalesced gather, 8 deep ----
        int cnt8 = (cnt + 7) & ~7;
        for (int s = 0; s < cnt8; s += 8) {
            unsigned int xw[8];
#pragma unroll
            for (int u = 0; u < 8; u++) {
                unsigned int ro =
                    (unsigned int)__builtin_amdgcn_readlane((int)rowElem, s + u);
                xw[u] = *(const unsigned int*)(xb + (size_t)ro + 2 * lane);
            }
#pragma unroll
            for (int u = 0; u < 8; u++) {
                float4 qa = *(const float4*)&qs[wid][s + u][0];   // broadcast
                float2 qb = *(const float2*)&qs[wid][s + u][4];
                float x0v = lo2f(xw[u]);
                float x1v = hi2f(xw[u]);
                a0[0] = fmaf(qa.x, x0v, a0[0]);
                a1[0] = fmaf(qa.x, x1v, a1[0]);
                a0[1] = fmaf(qa.y, x0v, a0[1]);
                a1[1] = fmaf(qa.y, x1v, a1[1]);
                a0[2] = fmaf(qa.z, x0v, a0[2]);
                a1[2] = fmaf(qa.z, x1v, a1[2]);
                a0[3] = fmaf(qa.w, x0v, a0[3]);
                a1[3] = fmaf(qa.w, x1v, a1[3]);
                a0[4] = fmaf(qb.x, x0v, a0[4]);
                a1[4] = fmaf(qb.x, x1v, a1[4]);
                a0[5] = fmaf(qb.y, x0v, a0[5]);
                a1[5] = fmaf(qb.y, x1v, a1[5]);
            }
        }
    }
    unsigned short* ar = agg + (size_t)node * 768;
#pragma unroll
    for (int h = 0; h < HH; h++) {
        *(unsigned int*)(ar + h * 128 + 2 * lane) = pk2(a0[h] * scale, a1[h] * scale);
    }
}

// ---------------- fused softmax + aggregation, CIN=6 (DMA staged) ---------
__global__ void __launch_bounds__(256) k_agg6(const unsigned short* __restrict__ xb,
                                              const float* __restrict__ p8,
                                              const void* __restrict__ cvec,
                                              const int* __restrict__ ssrc,
                                              const int* __restrict__ offs,
                                              float* __restrict__ agg,
                                              const int* __restrict__ flags) {
    __shared__ unsigned short stage6[4][64 * 8];     // 4 KB: 64 rows x 16 B
    __shared__ float qsf[4][64][8];                  // 8 KB: q[6] + rowbyte bits
    int f32 = flags[0];
    int wid = threadIdx.x >> 6, lane = threadIdx.x & 63;
    int node = (blockIdx.x * blockDim.x + threadIdx.x) >> 6;
    if (node >= NN) return;
    int s0 = offs[node], s1 = offs[node + 1];
    int deg = s1 - s0;
    float scale = 1.0f / (float)(deg > 0 ? deg : 1);
    const float* pn = p8 + (size_t)node * 8;
    float pd[HH];
#pragma unroll
    for (int h = 0; h < HH; h++) pd[h] = pn[h] - ldf(cvec, h, f32);

    float acc6 = 0.f;
    int hh6 = lane / 6, kk6 = lane - hh6 * 6;
    const char* xbase = (const char*)xb;
    for (int base = s0; base < s1; base += 64) {
        int cnt = (s1 - base < 64) ? (s1 - base) : 64;
        {
            int e = base + lane;
            float q0 = 0, q1 = 0, q2 = 0, q3 = 0, q4 = 0, q5 = 0;
            unsigned int rowByte = 0;
            if (e < s1) {
                int j = ssrc[e];
                const float* pj = p8 + (size_t)j * 8;
                float4 pa = *(const float4*)pj;
                float2 pb = *(const float2*)(pj + 4);
                float t0 = pa.x - pd[0], t1 = pa.y - pd[1], t2 = pa.z - pd[2];
                float t3 = pa.w - pd[3], t4 = pb.x - pd[4], t5 = pb.y - pd[5];
                float mx = fmaxf(fmaxf(fmaxf(t0, t1), fmaxf(t2, t3)), fmaxf(t4, t5));
                q0 = __expf(t0 - mx); q1 = __expf(t1 - mx); q2 = __expf(t2 - mx);
                q3 = __expf(t3 - mx); q4 = __expf(t4 - mx); q5 = __expf(t5 - mx);
                float inv = 1.0f / (q0 + q1 + q2 + q3 + q4 + q5);
                q0 *= inv; q1 *= inv; q2 *= inv; q3 *= inv; q4 *= inv; q5 *= inv;
                rowByte = (unsigned int)j * 16u;
            }
            float4 qa = {q0, q1, q2, q3};
            float4 qb = {q4, q5, __uint_as_float(rowByte), 0.f};
            *(float4*)&qsf[wid][lane][0] = qa;
            *(float4*)&qsf[wid][lane][4] = qb;
        }
        __builtin_amdgcn_sched_barrier(0);
#pragma unroll
        for (int t = 0; t < 4; t++) {
            int r = t * 16 + (lane >> 2);
            unsigned int rb = __float_as_uint(qsf[wid][r][6]);
            dma4(xbase + rb + (lane & 3) * 4, &stage6[wid][t * 128]);
        }
        __builtin_amdgcn_s_waitcnt(0x0f70);          // vmcnt(0) only
        __builtin_amdgcn_sched_barrier(0);
        if (lane < 36) {
            for (int s = 0; s < cnt; s++) {
                float qh = qsf[wid][s][hh6];
                float xv = u2f(stage6[wid][s * 8 + kk6]);
                acc6 = fmaf(qh, xv, acc6);
            }
        }
        __builtin_amdgcn_sched_barrier(0);
    }
    if (lane < 36) agg[(size_t)node * 36 + lane] = acc6 * scale;
}

// ---------------- fused weight repacks ----------------
__global__ void k_repack_all(const void* __restrict__ W1, const void* __restrict__ W2,
                             const void* __restrict__ W3, const void* __restrict__ W4,
                             const void* __restrict__ U4,
                             float* __restrict__ wstk1, unsigned short* __restrict__ wt2,
                             unsigned short* __restrict__ wt3, unsigned short* __restrict__ wt4,
                             unsigned short* __restrict__ u4,
                             const int* __restrict__ flags) {
    int f32 = flags[0];
    int idx = blockIdx.x * blockDim.x + threadIdx.x;
    if (idx < 4608) {
        int f = idx & 127, m = idx >> 7;
        int h = m / 6, k = m - h * 6;
        wstk1[idx] = ldf(W1, k * 768 + h * 128 + f, f32);
        return;
    }
    idx -= 4608;
    if (idx < 98304) {
        int f = idx / 768, m = idx % 768;
        int h = m >> 7, kk = m & 127;
        wt2[idx] = f2bu(ldf(W2, kk * 768 + h * 128 + f, f32));
        return;
    }
    idx -= 98304;
    if (idx < 98304) {
        int f = idx / 768, m = idx % 768;
        int h = m >> 7, kk = m & 127;
        wt3[idx] = f2bu(ldf(W3, kk * 768 + h * 128 + f, f32));
        return;
    }
    idx -= 98304;
    if (idx < 4096) {
        int n = idx >> 7, k = idx & 127;
        wt4[idx] = (n < 18) ? f2bu(ldf(W4, k * 18 + n, f32)) : (unsigned short)0;
        return;
    }
    idx -= 4096;
    if (idx < 2048) {
        int n = idx >> 7, k = idx & 127;
        u4[idx] = (n < 6) ? f2bu(ldf(U4, k * 6 + n, f32)) : (unsigned short)0;
    }
}

// ---------------- layer-1 GEMM (fp32, K=36), writes bf16 x ----------------
__global__ void __launch_bounds__(256) k_gemm_f32(const float* __restrict__ A,
                                                  const float* __restrict__ B,
                                                  const void* __restrict__ bias,
                                                  unsigned short* __restrict__ C,
                                                  int M, int K, int relu,
                                                  const int* __restrict__ flags) {
    int f32 = flags[0];
    __shared__ float As[16][68];
    __shared__ float Bs[16][128];
    int tid = threadIdx.x;
    int tx = tid & 15;
    int ty = tid >> 4;
    int bm = blockIdx.x * 64;
    int arow = tid >> 2, ak = (tid & 3) * 4;
    int brow = tid >> 4, bcol = (tid & 15) * 8;
    float acc[4][8] = {};
    for (int k0 = 0; k0 < K; k0 += 16) {
        float4 av = {0, 0, 0, 0};
        int gr = bm + arow;
        if (gr < M && (k0 + ak) < K) av = *(const float4*)(A + (size_t)gr * K + k0 + ak);
        As[ak + 0][arow] = av.x;
        As[ak + 1][arow] = av.y;
        As[ak + 2][arow] = av.z;
        As[ak + 3][arow] = av.w;
        float4 bv0 = {0, 0, 0, 0}, bv1 = {0, 0, 0, 0};
        if ((k0 + brow) < K) {
            const float* bp = B + (size_t)(k0 + brow) * 128 + bcol;
            bv0 = *(const float4*)bp;
            bv1 = *(const float4*)(bp + 4);
        }
        *(float4*)&Bs[brow][bcol]     = bv0;
        *(float4*)&Bs[brow][bcol + 4] = bv1;
        __syncthreads();
#pragma unroll
        for (int kk = 0; kk < 16; kk++) {
            float a_[4], b_[8];
#pragma unroll
            for (int j = 0; j < 4; j++) a_[j] = As[kk][ty * 4 + j];
#pragma unroll
            for (int j = 0; j < 8; j++) b_[j] = Bs[kk][tx * 8 + j];
#pragma unroll
            for (int i = 0; i < 4; i++)
#pragma unroll
                for (int j = 0; j < 8; j++) acc[i][j] = fmaf(a_[i], b_[j], acc[i][j]);
        }
        __syncthreads();
    }
#pragma unroll
    for (int i = 0; i < 4; i++) {
        int row = bm + ty * 4 + i;
        if (row >= M) continue;
#pragma unroll
        for (int j = 0; j < 8; j++) {
            int col = tx * 8 + j;
            float v = acc[i][j] + ldf(bias, col, f32);
            if (relu) v = fmaxf(v, 0.f);
            C[(size_t)row * 128 + col] = f2bu(v);
        }
    }
}

// ---------------- MFMA GEMM: C[M,128] = A[M,768]bf16 @ Wt^T + bias, ReLU ----
__global__ void __launch_bounds__(256) k_gemm_mfma(const unsigned short* __restrict__ A,
                                                   const unsigned short* __restrict__ Bt,
                                                   const void* __restrict__ bias,
                                                   unsigned short* __restrict__ C,
                                                   int M, int relu,
                                                   const int* __restrict__ flags) {
    constexpr int K = 768, BK = 64;
    __shared__ unsigned short As[64][72];
    __shared__ unsigned short Bs[128][72];
    int f32 = flags[0];
    int tid = threadIdx.x;
    int lane = tid & 63, wid = tid >> 6;
    int wm = wid & 1, wn = wid >> 1;
    int bm = blockIdx.x * 64;
    int l15 = lane & 15, lq = lane >> 4;
    f32x4 acc[2][4] = {};

    for (int k0 = 0; k0 < K; k0 += BK) {
#pragma unroll
        for (int cc = 0; cc < 2; cc++) {
            int c = tid + cc * 256;
            int r = c >> 3, kc = (c & 7) * 8;
            bf16x8 av = {};
            int gr = bm + r;
            if (gr < M) av = *(const bf16x8*)(A + (size_t)gr * K + k0 + kc);
            *(bf16x8*)&As[r][kc] = av;
        }
#pragma unroll
        for (int cc = 0; cc < 4; cc++) {
            int c = tid + cc * 256;
            int n = c >> 3, kc = (c & 7) * 8;
            *(bf16x8*)&Bs[n][kc] = *(const bf16x8*)(Bt + (size_t)n * K + k0 + kc);
        }
        __syncthreads();
#pragma unroll
        for (int ks = 0; ks < BK; ks += 32) {
            int koff = ks + lq * 8;
            bf16x8 af[2], bfr[4];
#pragma unroll
            for (int tm = 0; tm < 2; tm++)
                af[tm] = *(const bf16x8*)&As[wm * 32 + tm * 16 + l15][koff];
#pragma unroll
            for (int tn = 0; tn < 4; tn++)
                bfr[tn] = *(const bf16x8*)&Bs[wn * 64 + tn * 16 + l15][koff];
#pragma unroll
            for (int tm = 0; tm < 2; tm++)
#pragma unroll
                for (int tn = 0; tn < 4; tn++)
                    acc[tm][tn] = __builtin_amdgcn_mfma_f32_16x16x32_bf16(
                        af[tm], bfr[tn], acc[tm][tn], 0, 0, 0);
        }
        __syncthreads();
    }
#pragma unroll
    for (int tm = 0; tm < 2; tm++) {
#pragma unroll
        for (int tn = 0; tn < 4; tn++) {
            int col = wn * 64 + tn * 16 + l15;
            float bv = ldf(bias, col, f32);
#pragma unroll
            for (int r = 0; r < 4; r++) {
                int row = bm + wm * 32 + tm * 16 + lq * 4 + r;
                if (row < M) {
                    float v = acc[tm][tn][r] + bv;
                    if (relu) v = fmaxf(v, 0.f);
                    C[(size_t)row * 128 + col] = f2bu(v);
                }
            }
        }
    }
}

// ---------------- layer-4: y4 = x@W4 (bf16 out) AND p = x@u ---------------
__global__ void __launch_bounds__(256) k_y4p(const unsigned short* __restrict__ xb,
                                             const unsigned short* __restrict__ wt4,
                                             const unsigned short* __restrict__ u4,
                                             unsigned short* __restrict__ y4h,
                                             float* __restrict__ p8) {
    int tid = threadIdx.x;
    int lane = tid & 63, wid = tid >> 6;
    int l15 = lane & 15, lq = lane >> 4;
    int bm = blockIdx.x * 64 + wid * 16;
    f32x4 acc[2] = {};
    f32x4 accp = {};
#pragma unroll
    for (int ks = 0; ks < 128; ks += 32) {
        int koff = ks + lq * 8;
        bf16x8 af = {};
        int row = bm + l15;
        if (row < NN) af = *(const bf16x8*)(xb + (size_t)row * 128 + koff);
        bf16x8 b0 = *(const bf16x8*)(wt4 + (0 * 16 + l15) * 128 + koff);
        bf16x8 b1 = *(const bf16x8*)(wt4 + (1 * 16 + l15) * 128 + koff);
        bf16x8 bu = *(const bf16x8*)(u4 + l15 * 128 + koff);
        acc[0] = __builtin_amdgcn_mfma_f32_16x16x32_bf16(af, b0, acc[0], 0, 0, 0);
        acc[1] = __builtin_amdgcn_mfma_f32_16x16x32_bf16(af, b1, acc[1], 0, 0, 0);
        accp = __builtin_amdgcn_mfma_f32_16x16x32_bf16(af, bu, accp, 0, 0, 0);
    }
#pragma unroll
    for (int t = 0; t < 2; t++) {
#pragma unroll
        for (int r = 0; r < 4; r++) {
            int row = bm + lq * 4 + r;
            int col = t * 16 + l15;
            if (row < NN && col < 18) y4h[(size_t)row * 24 + col] = f2bu(acc[t][r]);
        }
    }
#pragma unroll
    for (int r = 0; r < 4; r++) {
        int row = bm + lq * 4 + r;
        if (row < NN && l15 < 6) p8[(size_t)row * 8 + l15] = accp[r];
    }
}

// ---------------- final layer: lane-per-edge over bf16 y4 -----------------
__global__ void __launch_bounds__(256) k_final_fast(const unsigned short* __restrict__ y4h,
                                                    const float* __restrict__ p8,
                                                    const void* __restrict__ cvec,
                                                    const int* __restrict__ ssrc,
                                                    const int* __restrict__ offs,
                                                    const void* __restrict__ bias,
                                                    void* __restrict__ out,
                                                    const int* __restrict__ flags) {
    int f32 = flags[0];
    int lane = threadIdx.x & 63;
    int node = (blockIdx.x * blockDim.x + threadIdx.x) >> 6;
    if (node >= NN) return;
    int s0 = offs[node], s1 = offs[node + 1];
    int deg = s1 - s0;
    float scale = 1.0f / (float)(deg > 0 ? deg : 1);
    const float* pn = p8 + (size_t)node * 8;
    float pd[HH];
#pragma unroll
    for (int h = 0; h < HH; h++) pd[h] = pn[h] - ldf(cvec, h, f32);

    float f0 = 0, f1 = 0, f2 = 0;
    for (int base = s0; base < s1; base += 64) {
        int e = base + lane;
        if (e < s1) {
            int j = ssrc[e];
            const float* pj = p8 + (size_t)j * 8;
            float4 pa = *(const float4*)pj;
            float2 pb = *(const float2*)(pj + 4);
            float t0 = pa.x - pd[0], t1 = pa.y - pd[1], t2 = pa.z - pd[2];
            float t3 = pa.w - pd[3], t4 = pb.x - pd[4], t5 = pb.y - pd[5];
            float mx = fmaxf(fmaxf(fmaxf(t0, t1), fmaxf(t2, t3)), fmaxf(t4, t5));
            float q0 = __expf(t0 - mx), q1 = __expf(t1 - mx), q2 = __expf(t2 - mx);
            float q3 = __expf(t3 - mx), q4 = __expf(t4 - mx), q5 = __expf(t5 - mx);
            float inv = 1.0f / (q0 + q1 + q2 + q3 + q4 + q5);
            float qa[6] = {q0 * inv, q1 * inv, q2 * inv, q3 * inv, q4 * inv, q5 * inv};
            const unsigned int* yr = (const unsigned int*)(y4h + (size_t)j * 24);
            uint4 ua = *(const uint4*)yr;
            uint4 ub = *(const uint4*)(yr + 4);
            unsigned int uc = yr[8];
            unsigned int d[9] = {ua.x, ua.y, ua.z, ua.w, ub.x, ub.y, ub.z, ub.w, uc};
            float yv[18];
#pragma unroll
            for (int c = 0; c < 18; c++)
                yv[c] = (c & 1) ? hi2f(d[c >> 1]) : lo2f(d[c >> 1]);
#pragma unroll
            for (int h = 0; h < HH; h++) {
                f0 = fmaf(qa[h], yv[3 * h + 0], f0);
                f1 = fmaf(qa[h], yv[3 * h + 1], f1);
                f2 = fmaf(qa[h], yv[3 * h + 2], f2);
            }
        }
    }
#pragma unroll
    for (int off = 32; off > 0; off >>= 1) {
        f0 += __shfl_down(f0, off, 64);
        f1 += __shfl_down(f1, off, 64);
        f2 += __shfl_down(f2, off, 64);
    }
    if (lane == 0) {
        float r0 = f0 * scale + ldf(bias, 0, f32);
        float r1 = f1 * scale + ldf(bias, 1, f32);
        float r2 = f2 * scale + ldf(bias, 2, f32);
        if (f32) {
            float* o = (float*)out;
            o[(size_t)node * 3 + 0] = r0;
            o[(size_t)node * 3 + 1] = r1;
            o[(size_t)node * 3 + 2] = r2;
        } else {
            __hip_bfloat16* o = (__hip_bfloat16*)out;
            o[(size_t)node * 3 + 0] = __float2bfloat16(r0);
            o[(size_t)node * 3 + 1] = __float2bfloat16(r1);
            o[(size_t)node * 3 + 2] = __float2bfloat16(r2);
        }
    }
}

extern "C" void kernel_launch(void* const* d_in, const int* in_sizes, int n_in,
                              void* d_out, int out_size, void* d_ws, size_t ws_size,
                              hipStream_t stream) {
    (void)in_sizes; (void)n_in; (void)out_size; (void)ws_size;
    const void* pos = d_in[0];
    const void* nrm = d_in[1];
    const int* ei = (const int*)d_in[2];
    const void* W[4] = {d_in[3], d_in[7], d_in[11], d_in[15]};
    const void* U[4] = {d_in[4], d_in[8], d_in[12], d_in[16]};
    const void* Cc[4] = {d_in[5], d_in[9], d_in[13], d_in[17]};
    const void* Bb[4] = {d_in[6], d_in[10], d_in[14], d_in[18]};

    char* wp = (char*)d_ws;
    auto alloc = [&](size_t b) { void* r = (void*)wp; wp += (b + 255) & ~(size_t)255; return r; };
    unsigned short* xA  = (unsigned short*)alloc((size_t)NN * 128 * 2);
    unsigned short* xB  = (unsigned short*)alloc((size_t)NN * 128 * 2);
    unsigned short* x0b = (unsigned short*)alloc((size_t)NN * 8 * 2);
    float* p8     = (float*)alloc((size_t)NN * 8 * 4);
    unsigned short* y4h = (unsigned short*)alloc((size_t)NN * 24 * 2);
    int*   offs   = (int*)alloc((size_t)(NN + 1) * 4);
    int*   cntT   = (int*)alloc((size_t)NBK * SWG * 4);
    int*   base2  = (int*)alloc((size_t)(NBK * SWG + 1) * 4);
    int*   bsums  = (int*)alloc((size_t)256 * 4);
    int*   bpre   = (int*)alloc((size_t)256 * 4);
    int*   flags  = (int*)alloc(256);
    int*   ssrc   = (int*)alloc((size_t)NE * 4);
    unsigned int* ebuck = (unsigned int*)alloc((size_t)NE * 4);
    void*  aggv   = alloc((size_t)NN * 768 * 2);
    float* wstk1  = (float*)alloc((size_t)36 * 128 * 4);
    unsigned short* wt2 = (unsigned short*)alloc((size_t)128 * 768 * 2);
    unsigned short* wt3 = (unsigned short*)alloc((size_t)128 * 768 * 2);
    unsigned short* wt4 = (unsigned short*)alloc((size_t)32 * 128 * 2);
    unsigned short* u4  = (unsigned short*)alloc((size_t)16 * 128 * 2);
    unsigned short* agg_h = (unsigned short*)aggv;
    float* agg_f = (float*)aggv;

    const int NB = (NN + 255) / 256;
    const int NWB = (NN * 64 + 255) / 256;      // 256-thread wave-per-node grids
    const int GB = (NN + 63) / 64;
    const int NSC = NBK * SWG;                   // 50176

    k_detect<<<1, 256, 0, stream>>>(pos, ei, flags);
    k_sortA<<<SWG, 256, 0, stream>>>(ei, cntT, flags);
    k_scan_local<<<NBK, 256, 0, stream>>>(cntT, NSC, base2, bsums);
    k_scan_sums<<<1, 256, 0, stream>>>(bsums, bpre, base2, NSC, NBK);
    k_scan_add<<<NBK, 256, 0, stream>>>(base2, NSC, bpre);
    k_sortB<<<SWG, 256, 0, stream>>>(ei, base2, ebuck, flags);
    k_sortC<<<NBK, 256, 0, stream>>>(ebuck, base2, offs, ssrc);
    k_build_x0<<<NB, 256, 0, stream>>>(pos, nrm, U[0], x0b, p8, flags);
    k_repack_all<<<(207360 + 255) / 256, 256, 0, stream>>>(W[0], W[1], W[2], W[3], U[3],
                                                           wstk1, wt2, wt3, wt4, u4, flags);

    // ---- layer 1: 6 -> 128, relu (p fused into build_x0) ----
    k_agg6<<<NWB, 256, 0, stream>>>(x0b, p8, Cc[0], ssrc, offs, agg_f, flags);
    k_gemm_f32<<<GB, 256, 0, stream>>>(agg_f, wstk1, Bb[0], xA, NN, 36, 1, flags);

    // ---- layer 2: 128 -> 128, relu ----
    k_compute_p128<<<NWB, 256, 0, stream>>>(xA, U[1], p8, flags);
    k_agg128<<<NWB, 256, 0, stream>>>(xA, p8, Cc[1], ssrc, offs, agg_h, flags);
    k_gemm_mfma<<<GB, 256, 0, stream>>>(agg_h, wt2, Bb[1], xB, NN, 1, flags);

    // ---- layer 3: 128 -> 128, relu ----
    k_compute_p128<<<NWB, 256, 0, stream>>>(xB, U[2], p8, flags);
    k_agg128<<<NWB, 256, 0, stream>>>(xB, p8, Cc[2], ssrc, offs, agg_h, flags);
    k_gemm_mfma<<<GB, 256, 0, stream>>>(agg_h, wt3, Bb[2], xA, NN, 1, flags);

    // ---- layer 4: 128 -> 3 (transform-first; y4 bf16 + p fused) ----
    k_y4p<<<GB, 256, 0, stream>>>(xA, wt4, u4, y4h, p8);
    k_final_fast<<<NWB, 256, 0, stream>>>(y4h, p8, Cc[3], ssrc, offs, Bb[3], d_out, flags);
}

// Round 15
// 478.888 us; speedup vs baseline: 1.1980x; 1.1374x over previous
//
#include <hip/hip_runtime.h>
#include <hip/hip_bf16.h>

// FeaStConv x4 on MI355X.
//  (1) (xj-xi)@u = p[src]-p[dst] with p = x@u per node (p padded to [N,8]).
//  (2) layers 1-3: aggregate-then-transform (gather x 256B/edge -> Agg ->
//      dense MFMA GEMM). Layer 4: transform-first via k_y4p, final gathers
//      bf16 y4 rows (36B/edge).
// Round 15: p = x@u FUSED into the producing GEMM's epilogue (gemm_f32 ->
// layer-2 p, gemm_mfma#1 -> layer-3 p; y4p already fuses layer-4 p). Kills
// both k_compute_p128 dispatches + their 2x12.8MB x re-reads. p is computed
// from u2f(f2bu(v)) so it sees exactly the bf16 x that agg gathers.

#define HH 6
constexpr int NN = 50000;
constexpr int NE = 1600000;
constexpr int NBK = 196;           // buckets: dst>>8, covers 50176 nodes
constexpr int SWG = 256;           // sort workgroups
constexpr int EPW = NE / SWG;      // 6250 edges per sort wg

typedef __attribute__((ext_vector_type(8))) short bf16x8;
typedef __attribute__((ext_vector_type(4))) float f32x4;

static __device__ __forceinline__ float b2f(__hip_bfloat16 v) { return __bfloat162float(v); }
static __device__ __forceinline__ float u2f(unsigned short u) {
    return __uint_as_float(((unsigned int)u) << 16);
}
static __device__ __forceinline__ unsigned short f2bu(float v) {
    __hip_bfloat16 b = __float2bfloat16(v);
    return *reinterpret_cast<unsigned short*>(&b);
}
static __device__ __forceinline__ float lo2f(unsigned int w) {
    return __uint_as_float(w << 16);
}
static __device__ __forceinline__ float hi2f(unsigned int w) {
    return __uint_as_float(w & 0xffff0000u);
}
static __device__ __forceinline__ unsigned int pk2(float lo, float hi) {
    return ((unsigned int)f2bu(hi) << 16) | (unsigned int)f2bu(lo);
}
static __device__ __forceinline__ float ldf(const void* p, int i, int f32) {
    return f32 ? ((const float*)p)[i] : b2f(((const __hip_bfloat16*)p)[i]);
}
static __device__ __forceinline__ int ldi(const int* e32, int i, int i64) {
    return i64 ? e32[2 * i] : e32[i];
}
// async global->LDS: each lane copies 4B; lane i lands at ldst + i*4
static __device__ __forceinline__ void dma4(const void* g, void* l) {
    __builtin_amdgcn_global_load_lds(
        (const __attribute__((address_space(1))) void*)g,
        (__attribute__((address_space(3))) void*)l, 4, 0, 0);
}

// ---------------- dtype detection ----------------
__global__ void k_detect(const void* pos, const void* ei, int* flags) {
    __shared__ float smax[256];
    __shared__ int anynz;
    int t = threadIdx.x;
    if (t == 0) anynz = 0;
    const __hip_bfloat16* pb = (const __hip_bfloat16*)pos;
    float m = 0.f;
    for (int i = t; i < 2048; i += 256) {
        float v = fabsf(b2f(pb[i]));
        if (v != v) v = 1e30f;
        m = fmaxf(m, v);
    }
    smax[t] = m;
    __syncthreads();
    for (int s = 128; s > 0; s >>= 1) {
        if (t < s) smax[t] = fmaxf(smax[t], smax[t + s]);
        __syncthreads();
    }
    const int* e32 = (const int*)ei;
    if (t < 128 && e32[2 * t + 1] != 0) anynz = 1;
    __syncthreads();
    if (t == 0) {
        flags[0] = (smax[0] > 1e6f) ? 1 : 0;
        flags[1] = anynz ? 0 : 1;
    }
}

// ---------------- input assembly + layer-1 p: x0 bf16 [N,8]; p8 [N,8] -----
__global__ void k_build_x0(const void* __restrict__ pos, const void* __restrict__ nrm,
                           const void* __restrict__ u1,
                           unsigned short* __restrict__ x0b, float* __restrict__ p8,
                           const int* __restrict__ flags) {
    int f32 = flags[0];
    int i = blockIdx.x * blockDim.x + threadIdx.x;
    if (i >= NN) return;
    float xv[6];
#pragma unroll
    for (int j = 0; j < 3; j++) {
        unsigned short a = f32 ? f2bu(((const float*)pos)[i * 3 + j])
                               : ((const unsigned short*)pos)[i * 3 + j];
        unsigned short b = f32 ? f2bu(((const float*)nrm)[i * 3 + j])
                               : ((const unsigned short*)nrm)[i * 3 + j];
        x0b[i * 8 + j]     = a;
        x0b[i * 8 + 3 + j] = b;
        xv[j]     = u2f(a);
        xv[3 + j] = u2f(b);
    }
    x0b[i * 8 + 6] = 0;
    x0b[i * 8 + 7] = 0;
    float acc[HH] = {};
#pragma unroll
    for (int k = 0; k < 6; k++)
#pragma unroll
        for (int h = 0; h < HH; h++) acc[h] = fmaf(xv[k], ldf(u1, k * HH + h, f32), acc[h]);
#pragma unroll
    for (int h = 0; h < HH; h++) p8[(size_t)i * 8 + h] = acc[h];
}

// ---------------- CSR build: two-level counting sort ----------------
__global__ void __launch_bounds__(256) k_sortA(const int* __restrict__ ei,
                                               int* __restrict__ cntT,
                                               const int* __restrict__ flags) {
    __shared__ int hist[NBK];
    int i64 = flags[1];
    int t = threadIdx.x, w = blockIdx.x;
    for (int b = t; b < NBK; b += 256) hist[b] = 0;
    __syncthreads();
    int start = w * EPW, end = start + EPW;
    for (int e = start + t; e < end; e += 256) {
        int d = ldi(ei, NE + e, i64);
        atomicAdd(&hist[d >> 8], 1);
    }
    __syncthreads();
    for (int b = t; b < NBK; b += 256) cntT[b * SWG + w] = hist[b];
}

// -------- 3-phase exclusive scan over cntT[NBK*SWG] --------
__global__ void __launch_bounds__(256) k_scan_local(const int* __restrict__ a, int n,
                                                    int* __restrict__ o,
                                                    int* __restrict__ bsums) {
    __shared__ int ws[4];
    int b = blockIdx.x, t = threadIdx.x, lane = t & 63, wid = t >> 6;
    int idx = b * 256 + t;
    int v = (idx < n) ? a[idx] : 0;
    int incl = v;
#pragma unroll
    for (int off = 1; off < 64; off <<= 1) {
        int nb = __shfl_up(incl, off, 64);
        if (lane >= off) incl += nb;
    }
    if (lane == 63) ws[wid] = incl;
    __syncthreads();
    int wpre = 0, tot = 0;
#pragma unroll
    for (int wi = 0; wi < 4; wi++) {
        int s = ws[wi];
        if (wi < wid) wpre += s;
        tot += s;
    }
    if (idx < n) o[idx] = wpre + incl - v;
    if (t == 0) bsums[b] = tot;
}

__global__ void __launch_bounds__(256) k_scan_sums(const int* __restrict__ bsums,
                                                   int* __restrict__ bpre,
                                                   int* __restrict__ o, int n, int nb) {
    __shared__ int ws[4];
    int t = threadIdx.x, lane = t & 63, wid = t >> 6;
    int v = (t < nb) ? bsums[t] : 0;
    int incl = v;
#pragma unroll
    for (int off = 1; off < 64; off <<= 1) {
        int nbv = __shfl_up(incl, off, 64);
        if (lane >= off) incl += nbv;
    }
    if (lane == 63) ws[wid] = incl;
    __syncthreads();
    int wpre = 0, tot = 0;
#pragma unroll
    for (int wi = 0; wi < 4; wi++) {
        int s = ws[wi];
        if (wi < wid) wpre += s;
        tot += s;
    }
    if (t < nb) bpre[t] = wpre + incl - v;
    if (t == 0) o[n] = tot;
}

__global__ void __launch_bounds__(256) k_scan_add(int* __restrict__ o, int n,
                                                  const int* __restrict__ bpre) {
    int idx = blockIdx.x * 256 + threadIdx.x;
    if (idx < n) o[idx] += bpre[blockIdx.x];
}

// stage B: scatter packed {dloc,src} into per-(bucket,wg) contiguous ranges
__global__ void __launch_bounds__(256) k_sortB(const int* __restrict__ ei,
                                               const int* __restrict__ base2,
                                               unsigned int* __restrict__ ebuck,
                                               const int* __restrict__ flags) {
    __shared__ int cur[NBK];
    int i64 = flags[1];
    int t = threadIdx.x, w = blockIdx.x;
    for (int b = t; b < NBK; b += 256) cur[b] = base2[b * SWG + w];
    __syncthreads();
    int start = w * EPW, end = start + EPW;
    for (int e = start + t; e < end; e += 256) {
        int s = ldi(ei, e, i64), d = ldi(ei, NE + e, i64);
        int slot = atomicAdd(&cur[d >> 8], 1);
        ebuck[slot] = (unsigned int)s | ((unsigned int)(d & 255) << 16);
    }
}

// stage C: LDS counting sort within one bucket; writes offs + fine scatter
__global__ void __launch_bounds__(256) k_sortC(const unsigned int* __restrict__ ebuck,
                                               const int* __restrict__ base2,
                                               int* __restrict__ offs,
                                               int* __restrict__ ssrc) {
    __shared__ int cnt[256];
    __shared__ int ws[4];
    int t = threadIdx.x, b = blockIdx.x;
    int lane = t & 63, wid = t >> 6;
    cnt[t] = 0;
    __syncthreads();
    int bs = base2[b * SWG], be = base2[(b + 1) * SWG];
    for (int e = bs + t; e < be; e += 256)
        atomicAdd(&cnt[(ebuck[e] >> 16) & 255], 1);
    __syncthreads();
    int v = cnt[t];
    int incl = v;
#pragma unroll
    for (int off = 1; off < 64; off <<= 1) {
        int nb = __shfl_up(incl, off, 64);
        if (lane >= off) incl += nb;
    }
    if (lane == 63) ws[wid] = incl;
    __syncthreads();
    int wpre = 0;
#pragma unroll
    for (int wi = 0; wi < 4; wi++)
        if (wi < wid) wpre += ws[wi];
    int excl = wpre + incl - v;
    int gn = b * 256 + t;
    if (gn <= NN) offs[gn] = bs + excl;
    __syncthreads();
    cnt[t] = bs + excl;                // becomes the scatter cursor
    __syncthreads();
    for (int e = bs + t; e < be; e += 256) {
        unsigned int rec = ebuck[e];
        int slot = atomicAdd(&cnt[(rec >> 16) & 255], 1);
        ssrc[slot] = (int)(rec & 0xffffu);
    }
}

// ---------------- fused softmax + aggregation, CIN=128 (r12 structure) ----
__global__ void __launch_bounds__(256) k_agg128(const unsigned short* __restrict__ xb,
                                                const float* __restrict__ p8,
                                                const void* __restrict__ cvec,
                                                const int* __restrict__ ssrc,
                                                const int* __restrict__ offs,
                                                unsigned short* __restrict__ agg,
                                                const int* __restrict__ flags) {
    __shared__ float qs[4][64][8];   // 8 KB: q0..q5 + pad
    int f32 = flags[0];
    int wid = threadIdx.x >> 6, lane = threadIdx.x & 63;
    int node = (blockIdx.x * blockDim.x + threadIdx.x) >> 6;
    if (node >= NN) return;
    int s0 = offs[node], s1 = offs[node + 1];
    int deg = s1 - s0;
    float scale = 1.0f / (float)(deg > 0 ? deg : 1);
    const float* pn = p8 + (size_t)node * 8;
    float pd[HH];
#pragma unroll
    for (int h = 0; h < HH; h++) pd[h] = pn[h] - ldf(cvec, h, f32);

    float a0[HH] = {}, a1[HH] = {};
    for (int base = s0; base < s1; base += 64) {
        int cnt = (s1 - base < 64) ? (s1 - base) : 64;
        // ---- phase A: lane = edge; fp32 q -> LDS; rowElem stays in reg ----
        unsigned int rowElem = 0;
        {
            int e = base + lane;
            float q0 = 0, q1 = 0, q2 = 0, q3 = 0, q4 = 0, q5 = 0;
            if (e < s1) {
                int j = ssrc[e];
                const float* pj = p8 + (size_t)j * 8;
                float4 pa = *(const float4*)pj;
                float2 pb = *(const float2*)(pj + 4);
                float t0 = pa.x - pd[0], t1 = pa.y - pd[1], t2 = pa.z - pd[2];
                float t3 = pa.w - pd[3], t4 = pb.x - pd[4], t5 = pb.y - pd[5];
                float mx = fmaxf(fmaxf(fmaxf(t0, t1), fmaxf(t2, t3)), fmaxf(t4, t5));
                q0 = __expf(t0 - mx); q1 = __expf(t1 - mx); q2 = __expf(t2 - mx);
                q3 = __expf(t3 - mx); q4 = __expf(t4 - mx); q5 = __expf(t5 - mx);
                float inv = 1.0f / (q0 + q1 + q2 + q3 + q4 + q5);
                q0 *= inv; q1 *= inv; q2 *= inv; q3 *= inv; q4 *= inv; q5 *= inv;
                rowElem = (unsigned int)j * 128u;
            }
            float4 qa = {q0, q1, q2, q3};
            float2 qb = {q4, q5};
            *(float4*)&qs[wid][lane][0] = qa;
            *(float2*)&qs[wid][lane][4] = qb;
        }
        // ---- phase B: broadcast LDS q + coalesced gather, 8 deep ----
        int cnt8 = (cnt + 7) & ~7;
        for (int s = 0; s < cnt8; s += 8) {
            unsigned int xw[8];
#pragma unroll
            for (int u = 0; u < 8; u++) {
                unsigned int ro =
                    (unsigned int)__builtin_amdgcn_readlane((int)rowElem, s + u);
                xw[u] = *(const unsigned int*)(xb + (size_t)ro + 2 * lane);
            }
#pragma unroll
            for (int u = 0; u < 8; u++) {
                float4 qa = *(const float4*)&qs[wid][s + u][0];   // broadcast
                float2 qb = *(const float2*)&qs[wid][s + u][4];
                float x0v = lo2f(xw[u]);
                float x1v = hi2f(xw[u]);
                a0[0] = fmaf(qa.x, x0v, a0[0]);
                a1[0] = fmaf(qa.x, x1v, a1[0]);
                a0[1] = fmaf(qa.y, x0v, a0[1]);
                a1[1] = fmaf(qa.y, x1v, a1[1]);
                a0[2] = fmaf(qa.z, x0v, a0[2]);
                a1[2] = fmaf(qa.z, x1v, a1[2]);
                a0[3] = fmaf(qa.w, x0v, a0[3]);
                a1[3] = fmaf(qa.w, x1v, a1[3]);
                a0[4] = fmaf(qb.x, x0v, a0[4]);
                a1[4] = fmaf(qb.x, x1v, a1[4]);
                a0[5] = fmaf(qb.y, x0v, a0[5]);
                a1[5] = fmaf(qb.y, x1v, a1[5]);
            }
        }
    }
    unsigned short* ar = agg + (size_t)node * 768;
#pragma unroll
    for (int h = 0; h < HH; h++) {
        *(unsigned int*)(ar + h * 128 + 2 * lane) = pk2(a0[h] * scale, a1[h] * scale);
    }
}

// ---------------- fused softmax + aggregation, CIN=6 (DMA staged) ---------
__global__ void __launch_bounds__(256) k_agg6(const unsigned short* __restrict__ xb,
                                              const float* __restrict__ p8,
                                              const void* __restrict__ cvec,
                                              const int* __restrict__ ssrc,
                                              const int* __restrict__ offs,
                                              float* __restrict__ agg,
                                              const int* __restrict__ flags) {
    __shared__ unsigned short stage6[4][64 * 8];     // 4 KB: 64 rows x 16 B
    __shared__ float qsf[4][64][8];                  // 8 KB: q[6] + rowbyte bits
    int f32 = flags[0];
    int wid = threadIdx.x >> 6, lane = threadIdx.x & 63;
    int node = (blockIdx.x * blockDim.x + threadIdx.x) >> 6;
    if (node >= NN) return;
    int s0 = offs[node], s1 = offs[node + 1];
    int deg = s1 - s0;
    float scale = 1.0f / (float)(deg > 0 ? deg : 1);
    const float* pn = p8 + (size_t)node * 8;
    float pd[HH];
#pragma unroll
    for (int h = 0; h < HH; h++) pd[h] = pn[h] - ldf(cvec, h, f32);

    float acc6 = 0.f;
    int hh6 = lane / 6, kk6 = lane - hh6 * 6;
    const char* xbase = (const char*)xb;
    for (int base = s0; base < s1; base += 64) {
        int cnt = (s1 - base < 64) ? (s1 - base) : 64;
        {
            int e = base + lane;
            float q0 = 0, q1 = 0, q2 = 0, q3 = 0, q4 = 0, q5 = 0;
            unsigned int rowByte = 0;
            if (e < s1) {
                int j = ssrc[e];
                const float* pj = p8 + (size_t)j * 8;
                float4 pa = *(const float4*)pj;
                float2 pb = *(const float2*)(pj + 4);
                float t0 = pa.x - pd[0], t1 = pa.y - pd[1], t2 = pa.z - pd[2];
                float t3 = pa.w - pd[3], t4 = pb.x - pd[4], t5 = pb.y - pd[5];
                float mx = fmaxf(fmaxf(fmaxf(t0, t1), fmaxf(t2, t3)), fmaxf(t4, t5));
                q0 = __expf(t0 - mx); q1 = __expf(t1 - mx); q2 = __expf(t2 - mx);
                q3 = __expf(t3 - mx); q4 = __expf(t4 - mx); q5 = __expf(t5 - mx);
                float inv = 1.0f / (q0 + q1 + q2 + q3 + q4 + q5);
                q0 *= inv; q1 *= inv; q2 *= inv; q3 *= inv; q4 *= inv; q5 *= inv;
                rowByte = (unsigned int)j * 16u;
            }
            float4 qa = {q0, q1, q2, q3};
            float4 qb = {q4, q5, __uint_as_float(rowByte), 0.f};
            *(float4*)&qsf[wid][lane][0] = qa;
            *(float4*)&qsf[wid][lane][4] = qb;
        }
        __builtin_amdgcn_sched_barrier(0);
#pragma unroll
        for (int t = 0; t < 4; t++) {
            int r = t * 16 + (lane >> 2);
            unsigned int rb = __float_as_uint(qsf[wid][r][6]);
            dma4(xbase + rb + (lane & 3) * 4, &stage6[wid][t * 128]);
        }
        __builtin_amdgcn_s_waitcnt(0x0f70);          // vmcnt(0) only
        __builtin_amdgcn_sched_barrier(0);
        if (lane < 36) {
            for (int s = 0; s < cnt; s++) {
                float qh = qsf[wid][s][hh6];
                float xv = u2f(stage6[wid][s * 8 + kk6]);
                acc6 = fmaf(qh, xv, acc6);
            }
        }
        __builtin_amdgcn_sched_barrier(0);
    }
    if (lane < 36) agg[(size_t)node * 36 + lane] = acc6 * scale;
}

// ---------------- fused weight repacks ----------------
// wstk1 fp32 [36,128]; wt2,wt3 bf16 [128,768] (B^T); wt4 bf16 [32,128];
// u4 bf16 [16,128]; uf2,uf3 fp32 [128*6] (straight copy of U2/U3).
__global__ void k_repack_all(const void* __restrict__ W1, const void* __restrict__ W2,
                             const void* __restrict__ W3, const void* __restrict__ W4,
                             const void* __restrict__ U2, const void* __restrict__ U3,
                             const void* __restrict__ U4,
                             float* __restrict__ wstk1, unsigned short* __restrict__ wt2,
                             unsigned short* __restrict__ wt3, unsigned short* __restrict__ wt4,
                             unsigned short* __restrict__ u4,
                             float* __restrict__ uf2, float* __restrict__ uf3,
                             const int* __restrict__ flags) {
    int f32 = flags[0];
    int idx = blockIdx.x * blockDim.x + threadIdx.x;
    if (idx < 4608) {
        int f = idx & 127, m = idx >> 7;
        int h = m / 6, k = m - h * 6;
        wstk1[idx] = ldf(W1, k * 768 + h * 128 + f, f32);
        return;
    }
    idx -= 4608;
    if (idx < 98304) {
        int f = idx / 768, m = idx % 768;
        int h = m >> 7, kk = m & 127;
        wt2[idx] = f2bu(ldf(W2, kk * 768 + h * 128 + f, f32));
        return;
    }
    idx -= 98304;
    if (idx < 98304) {
        int f = idx / 768, m = idx % 768;
        int h = m >> 7, kk = m & 127;
        wt3[idx] = f2bu(ldf(W3, kk * 768 + h * 128 + f, f32));
        return;
    }
    idx -= 98304;
    if (idx < 4096) {
        int n = idx >> 7, k = idx & 127;
        wt4[idx] = (n < 18) ? f2bu(ldf(W4, k * 18 + n, f32)) : (unsigned short)0;
        return;
    }
    idx -= 4096;
    if (idx < 2048) {
        int n = idx >> 7, k = idx & 127;
        u4[idx] = (n < 6) ? f2bu(ldf(U4, k * 6 + n, f32)) : (unsigned short)0;
        return;
    }
    idx -= 2048;
    if (idx < 768) {
        uf2[idx] = ldf(U2, idx, f32);
        return;
    }
    idx -= 768;
    if (idx < 768) {
        uf3[idx] = ldf(U3, idx, f32);
    }
}

// ---------------- layer-1 GEMM (fp32, K=36), bf16 x out + fused p ---------
__global__ void __launch_bounds__(256) k_gemm_f32(const float* __restrict__ A,
                                                  const float* __restrict__ B,
                                                  const void* __restrict__ bias,
                                                  const float* __restrict__ uf,
                                                  unsigned short* __restrict__ C,
                                                  float* __restrict__ p8,
                                                  int M, int K, int relu,
                                                  const int* __restrict__ flags) {
    int f32 = flags[0];
    __shared__ float As[16][68];
    __shared__ float Bs[16][128];
    int tid = threadIdx.x;
    int tx = tid & 15;
    int ty = tid >> 4;
    int bm = blockIdx.x * 64;
    int arow = tid >> 2, ak = (tid & 3) * 4;
    int brow = tid >> 4, bcol = (tid & 15) * 8;
    float acc[4][8] = {};
    for (int k0 = 0; k0 < K; k0 += 16) {
        float4 av = {0, 0, 0, 0};
        int gr = bm + arow;
        if (gr < M && (k0 + ak) < K) av = *(const float4*)(A + (size_t)gr * K + k0 + ak);
        As[ak + 0][arow] = av.x;
        As[ak + 1][arow] = av.y;
        As[ak + 2][arow] = av.z;
        As[ak + 3][arow] = av.w;
        float4 bv0 = {0, 0, 0, 0}, bv1 = {0, 0, 0, 0};
        if ((k0 + brow) < K) {
            const float* bp = B + (size_t)(k0 + brow) * 128 + bcol;
            bv0 = *(const float4*)bp;
            bv1 = *(const float4*)(bp + 4);
        }
        *(float4*)&Bs[brow][bcol]     = bv0;
        *(float4*)&Bs[brow][bcol + 4] = bv1;
        __syncthreads();
#pragma unroll
        for (int kk = 0; kk < 16; kk++) {
            float a_[4], b_[8];
#pragma unroll
            for (int j = 0; j < 4; j++) a_[j] = As[kk][ty * 4 + j];
#pragma unroll
            for (int j = 0; j < 8; j++) b_[j] = Bs[kk][tx * 8 + j];
#pragma unroll
            for (int i = 0; i < 4; i++)
#pragma unroll
                for (int j = 0; j < 8; j++) acc[i][j] = fmaf(a_[i], b_[j], acc[i][j]);
        }
        __syncthreads();
    }
    // epilogue: store bf16 C; overwrite acc with bf16-rounded value for p
#pragma unroll
    for (int i = 0; i < 4; i++) {
        int row = bm + ty * 4 + i;
#pragma unroll
        for (int j = 0; j < 8; j++) {
            int col = tx * 8 + j;
            float v = acc[i][j] + ldf(bias, col, f32);
            if (relu) v = fmaxf(v, 0.f);
            unsigned short hv = f2bu(v);
            if (row < M) C[(size_t)row * 128 + col] = hv;
            acc[i][j] = u2f(hv);
        }
    }
    // fused p = x @ u: partial over this lane's 8 cols, reduce over tx
    float uu[8][HH];
#pragma unroll
    for (int j = 0; j < 8; j++) {
        int col = tx * 8 + j;
#pragma unroll
        for (int h = 0; h < HH; h++) uu[j][h] = uf[col * HH + h];
    }
    float pp[4][HH] = {};
#pragma unroll
    for (int i = 0; i < 4; i++)
#pragma unroll
        for (int j = 0; j < 8; j++)
#pragma unroll
            for (int h = 0; h < HH; h++) pp[i][h] = fmaf(acc[i][j], uu[j][h], pp[i][h]);
#pragma unroll
    for (int m = 1; m < 16; m <<= 1)
#pragma unroll
        for (int i = 0; i < 4; i++)
#pragma unroll
            for (int h = 0; h < HH; h++) pp[i][h] += __shfl_xor(pp[i][h], m, 64);
    if (tx == 0) {
#pragma unroll
        for (int i = 0; i < 4; i++) {
            int row = bm + ty * 4 + i;
            if (row < M) {
#pragma unroll
                for (int h = 0; h < HH; h++) p8[(size_t)row * 8 + h] = pp[i][h];
            }
        }
    }
}

// ---------------- MFMA GEMM: C[M,128] = A[M,768]bf16 @ Wt^T + bias, ReLU --
// Optional fused p = x@u (p8 != nullptr): per-lane partials over its 4 cols,
// shfl_xor reduce over l15, cross-wave combine via LDS overlay on As.
__global__ void __launch_bounds__(256) k_gemm_mfma(const unsigned short* __restrict__ A,
                                                   const unsigned short* __restrict__ Bt,
                                                   const void* __restrict__ bias,
                                                   const float* __restrict__ uf,
                                                   unsigned short* __restrict__ C,
                                                   float* __restrict__ p8,
                                                   int M, int relu,
                                                   const int* __restrict__ flags) {
    constexpr int K = 768, BK = 64;
    __shared__ unsigned short As[64][72];
    __shared__ unsigned short Bs[128][72];
    int f32 = flags[0];
    int tid = threadIdx.x;
    int lane = tid & 63, wid = tid >> 6;
    int wm = wid & 1, wn = wid >> 1;
    int bm = blockIdx.x * 64;
    int l15 = lane & 15, lq = lane >> 4;
    f32x4 acc[2][4] = {};

    for (int k0 = 0; k0 < K; k0 += BK) {
#pragma unroll
        for (int cc = 0; cc < 2; cc++) {
            int c = tid + cc * 256;
            int r = c >> 3, kc = (c & 7) * 8;
            bf16x8 av = {};
            int gr = bm + r;
            if (gr < M) av = *(const bf16x8*)(A + (size_t)gr * K + k0 + kc);
            *(bf16x8*)&As[r][kc] = av;
        }
#pragma unroll
        for (int cc = 0; cc < 4; cc++) {
            int c = tid + cc * 256;
            int n = c >> 3, kc = (c & 7) * 8;
            *(bf16x8*)&Bs[n][kc] = *(const bf16x8*)(Bt + (size_t)n * K + k0 + kc);
        }
        __syncthreads();
#pragma unroll
        for (int ks = 0; ks < BK; ks += 32) {
            int koff = ks + lq * 8;
            bf16x8 af[2], bfr[4];
#pragma unroll
            for (int tm = 0; tm < 2; tm++)
                af[tm] = *(const bf16x8*)&As[wm * 32 + tm * 16 + l15][koff];
#pragma unroll
            for (int tn = 0; tn < 4; tn++)
                bfr[tn] = *(const bf16x8*)&Bs[wn * 64 + tn * 16 + l15][koff];
#pragma unroll
            for (int tm = 0; tm < 2; tm++)
#pragma unroll
                for (int tn = 0; tn < 4; tn++)
                    acc[tm][tn] = __builtin_amdgcn_mfma_f32_16x16x32_bf16(
                        af[tm], bfr[tn], acc[tm][tn], 0, 0, 0);
        }
        __syncthreads();
    }
    // epilogue: bias+relu+bf16 store; overwrite acc with rounded values
#pragma unroll
    for (int tm = 0; tm < 2; tm++) {
#pragma unroll
        for (int tn = 0; tn < 4; tn++) {
            int col = wn * 64 + tn * 16 + l15;
            float bv = ldf(bias, col, f32);
#pragma unroll
            for (int r = 0; r < 4; r++) {
                int row = bm + wm * 32 + tm * 16 + lq * 4 + r;
                float v = acc[tm][tn][r] + bv;
                if (relu) v = fmaxf(v, 0.f);
                unsigned short hv = f2bu(v);
                if (row < M) C[(size_t)row * 128 + col] = hv;
                acc[tm][tn][r] = u2f(hv);
            }
        }
    }
    if (p8) {
        float* pl = (float*)&As[0][0];     // 1.5 KB overlay (As is dead now)
        if (tid < 384) pl[tid] = 0.f;
        float uu[4][HH];
#pragma unroll
        for (int tn = 0; tn < 4; tn++) {
            int col = wn * 64 + tn * 16 + l15;
#pragma unroll
            for (int h = 0; h < HH; h++) uu[tn][h] = uf[col * HH + h];
        }
        __syncthreads();
#pragma unroll
        for (int tm = 0; tm < 2; tm++) {
            float pp[4][HH] = {};
#pragma unroll
            for (int tn = 0; tn < 4; tn++)
#pragma unroll
                for (int r = 0; r < 4; r++)
#pragma unroll
                    for (int h = 0; h < HH; h++)
                        pp[r][h] = fmaf(acc[tm][tn][r], uu[tn][h], pp[r][h]);
#pragma unroll
            for (int m = 1; m < 16; m <<= 1)
#pragma unroll
                for (int r = 0; r < 4; r++)
#pragma unroll
                    for (int h = 0; h < HH; h++)
                        pp[r][h] += __shfl_xor(pp[r][h], m, 64);
            if (l15 == 0) {
#pragma unroll
                for (int r = 0; r < 4; r++) {
                    int lrow = wm * 32 + tm * 16 + lq * 4 + r;
#pragma unroll
                    for (int h = 0; h < HH; h++)
                        atomicAdd(&pl[lrow * HH + h], pp[r][h]);
                }
            }
        }
        __syncthreads();
        if (tid < 384) {
            int lrow = tid / 6;
            int grow = bm + lrow;
            if (grow < M) p8[(size_t)grow * 8 + (tid - lrow * 6)] = pl[tid];
        }
    }
}

// ---------------- layer-4: y4 = x@W4 (bf16 out) AND p = x@u ---------------
__global__ void __launch_bounds__(256) k_y4p(const unsigned short* __restrict__ xb,
                                             const unsigned short* __restrict__ wt4,
                                             const unsigned short* __restrict__ u4,
                                             unsigned short* __restrict__ y4h,
                                             float* __restrict__ p8) {
    int tid = threadIdx.x;
    int lane = tid & 63, wid = tid >> 6;
    int l15 = lane & 15, lq = lane >> 4;
    int bm = blockIdx.x * 64 + wid * 16;
    f32x4 acc[2] = {};
    f32x4 accp = {};
#pragma unroll
    for (int ks = 0; ks < 128; ks += 32) {
        int koff = ks + lq * 8;
        bf16x8 af = {};
        int row = bm + l15;
        if (row < NN) af = *(const bf16x8*)(xb + (size_t)row * 128 + koff);
        bf16x8 b0 = *(const bf16x8*)(wt4 + (0 * 16 + l15) * 128 + koff);
        bf16x8 b1 = *(const bf16x8*)(wt4 + (1 * 16 + l15) * 128 + koff);
        bf16x8 bu = *(const bf16x8*)(u4 + l15 * 128 + koff);
        acc[0] = __builtin_amdgcn_mfma_f32_16x16x32_bf16(af, b0, acc[0], 0, 0, 0);
        acc[1] = __builtin_amdgcn_mfma_f32_16x16x32_bf16(af, b1, acc[1], 0, 0, 0);
        accp = __builtin_amdgcn_mfma_f32_16x16x32_bf16(af, bu, accp, 0, 0, 0);
    }
#pragma unroll
    for (int t = 0; t < 2; t++) {
#pragma unroll
        for (int r = 0; r < 4; r++) {
            int row = bm + lq * 4 + r;
            int col = t * 16 + l15;
            if (row < NN && col < 18) y4h[(size_t)row * 24 + col] = f2bu(acc[t][r]);
        }
    }
#pragma unroll
    for (int r = 0; r < 4; r++) {
        int row = bm + lq * 4 + r;
        if (row < NN && l15 < 6) p8[(size_t)row * 8 + l15] = accp[r];
    }
}

// ---------------- final layer: lane-per-edge over bf16 y4 -----------------
__global__ void __launch_bounds__(256) k_final_fast(const unsigned short* __restrict__ y4h,
                                                    const float* __restrict__ p8,
                                                    const void* __restrict__ cvec,
                                                    const int* __restrict__ ssrc,
                                                    const int* __restrict__ offs,
                                                    const void* __restrict__ bias,
                                                    void* __restrict__ out,
                                                    const int* __restrict__ flags) {
    int f32 = flags[0];
    int lane = threadIdx.x & 63;
    int node = (blockIdx.x * blockDim.x + threadIdx.x) >> 6;
    if (node >= NN) return;
    int s0 = offs[node], s1 = offs[node + 1];
    int deg = s1 - s0;
    float scale = 1.0f / (float)(deg > 0 ? deg : 1);
    const float* pn = p8 + (size_t)node * 8;
    float pd[HH];
#pragma unroll
    for (int h = 0; h < HH; h++) pd[h] = pn[h] - ldf(cvec, h, f32);

    float f0 = 0, f1 = 0, f2 = 0;
    for (int base = s0; base < s1; base += 64) {
        int e = base + lane;
        if (e < s1) {
            int j = ssrc[e];
            const float* pj = p8 + (size_t)j * 8;
            float4 pa = *(const float4*)pj;
            float2 pb = *(const float2*)(pj + 4);
            float t0 = pa.x - pd[0], t1 = pa.y - pd[1], t2 = pa.z - pd[2];
            float t3 = pa.w - pd[3], t4 = pb.x - pd[4], t5 = pb.y - pd[5];
            float mx = fmaxf(fmaxf(fmaxf(t0, t1), fmaxf(t2, t3)), fmaxf(t4, t5));
            float q0 = __expf(t0 - mx), q1 = __expf(t1 - mx), q2 = __expf(t2 - mx);
            float q3 = __expf(t3 - mx), q4 = __expf(t4 - mx), q5 = __expf(t5 - mx);
            float inv = 1.0f / (q0 + q1 + q2 + q3 + q4 + q5);
            float qa[6] = {q0 * inv, q1 * inv, q2 * inv, q3 * inv, q4 * inv, q5 * inv};
            const unsigned int* yr = (const unsigned int*)(y4h + (size_t)j * 24);
            uint4 ua = *(const uint4*)yr;
            uint4 ub = *(const uint4*)(yr + 4);
            unsigned int uc = yr[8];
            unsigned int d[9] = {ua.x, ua.y, ua.z, ua.w, ub.x, ub.y, ub.z, ub.w, uc};
            float yv[18];
#pragma unroll
            for (int c = 0; c < 18; c++)
                yv[c] = (c & 1) ? hi2f(d[c >> 1]) : lo2f(d[c >> 1]);
#pragma unroll
            for (int h = 0; h < HH; h++) {
                f0 = fmaf(qa[h], yv[3 * h + 0], f0);
                f1 = fmaf(qa[h], yv[3 * h + 1], f1);
                f2 = fmaf(qa[h], yv[3 * h + 2], f2);
            }
        }
    }
#pragma unroll
    for (int off = 32; off > 0; off >>= 1) {
        f0 += __shfl_down(f0, off, 64);
        f1 += __shfl_down(f1, off, 64);
        f2 += __shfl_down(f2, off, 64);
    }
    if (lane == 0) {
        float r0 = f0 * scale + ldf(bias, 0, f32);
        float r1 = f1 * scale + ldf(bias, 1, f32);
        float r2 = f2 * scale + ldf(bias, 2, f32);
        if (f32) {
            float* o = (float*)out;
            o[(size_t)node * 3 + 0] = r0;
            o[(size_t)node * 3 + 1] = r1;
            o[(size_t)node * 3 + 2] = r2;
        } else {
            __hip_bfloat16* o = (__hip_bfloat16*)out;
            o[(size_t)node * 3 + 0] = __float2bfloat16(r0);
            o[(size_t)node * 3 + 1] = __float2bfloat16(r1);
            o[(size_t)node * 3 + 2] = __float2bfloat16(r2);
        }
    }
}

extern "C" void kernel_launch(void* const* d_in, const int* in_sizes, int n_in,
                              void* d_out, int out_size, void* d_ws, size_t ws_size,
                              hipStream_t stream) {
    (void)in_sizes; (void)n_in; (void)out_size; (void)ws_size;
    const void* pos = d_in[0];
    const void* nrm = d_in[1];
    const int* ei = (const int*)d_in[2];
    const void* W[4] = {d_in[3], d_in[7], d_in[11], d_in[15]};
    const void* U[4] = {d_in[4], d_in[8], d_in[12], d_in[16]};
    const void* Cc[4] = {d_in[5], d_in[9], d_in[13], d_in[17]};
    const void* Bb[4] = {d_in[6], d_in[10], d_in[14], d_in[18]};

    char* wp = (char*)d_ws;
    auto alloc = [&](size_t b) { void* r = (void*)wp; wp += (b + 255) & ~(size_t)255; return r; };
    unsigned short* xA  = (unsigned short*)alloc((size_t)NN * 128 * 2);
    unsigned short* xB  = (unsigned short*)alloc((size_t)NN * 128 * 2);
    unsigned short* x0b = (unsigned short*)alloc((size_t)NN * 8 * 2);
    float* p8     = (float*)alloc((size_t)NN * 8 * 4);
    unsigned short* y4h = (unsigned short*)alloc((size_t)NN * 24 * 2);
    int*   offs   = (int*)alloc((size_t)(NN + 1) * 4);
    int*   cntT   = (int*)alloc((size_t)NBK * SWG * 4);
    int*   base2  = (int*)alloc((size_t)(NBK * SWG + 1) * 4);
    int*   bsums  = (int*)alloc((size_t)256 * 4);
    int*   bpre   = (int*)alloc((size_t)256 * 4);
    int*   flags  = (int*)alloc(256);
    int*   ssrc   = (int*)alloc((size_t)NE * 4);
    unsigned int* ebuck = (unsigned int*)alloc((size_t)NE * 4);
    void*  aggv   = alloc((size_t)NN * 768 * 2);
    float* wstk1  = (float*)alloc((size_t)36 * 128 * 4);
    unsigned short* wt2 = (unsigned short*)alloc((size_t)128 * 768 * 2);
    unsigned short* wt3 = (unsigned short*)alloc((size_t)128 * 768 * 2);
    unsigned short* wt4 = (unsigned short*)alloc((size_t)32 * 128 * 2);
    unsigned short* u4  = (unsigned short*)alloc((size_t)16 * 128 * 2);
    float* uf2    = (float*)alloc((size_t)768 * 4);
    float* uf3    = (float*)alloc((size_t)768 * 4);
    unsigned short* agg_h = (unsigned short*)aggv;
    float* agg_f = (float*)aggv;

    const int NB = (NN + 255) / 256;
    const int NWB = (NN * 64 + 255) / 256;      // 256-thread wave-per-node grids
    const int GB = (NN + 63) / 64;
    const int NSC = NBK * SWG;                   // 50176

    k_detect<<<1, 256, 0, stream>>>(pos, ei, flags);
    k_sortA<<<SWG, 256, 0, stream>>>(ei, cntT, flags);
    k_scan_local<<<NBK, 256, 0, stream>>>(cntT, NSC, base2, bsums);
    k_scan_sums<<<1, 256, 0, stream>>>(bsums, bpre, base2, NSC, NBK);
    k_scan_add<<<NBK, 256, 0, stream>>>(base2, NSC, bpre);
    k_sortB<<<SWG, 256, 0, stream>>>(ei, base2, ebuck, flags);
    k_sortC<<<NBK, 256, 0, stream>>>(ebuck, base2, offs, ssrc);
    k_build_x0<<<NB, 256, 0, stream>>>(pos, nrm, U[0], x0b, p8, flags);
    k_repack_all<<<(208896 + 255) / 256, 256, 0, stream>>>(W[0], W[1], W[2], W[3],
                                                           U[1], U[2], U[3],
                                                           wstk1, wt2, wt3, wt4, u4,
                                                           uf2, uf3, flags);

    // ---- layer 1: 6 -> 128, relu (p1 from build_x0; p2 fused in gemm) ----
    k_agg6<<<NWB, 256, 0, stream>>>(x0b, p8, Cc[0], ssrc, offs, agg_f, flags);
    k_gemm_f32<<<GB, 256, 0, stream>>>(agg_f, wstk1, Bb[0], uf2, xA, p8, NN, 36, 1, flags);

    // ---- layer 2: 128 -> 128, relu (p3 fused in gemm) ----
    k_agg128<<<NWB, 256, 0, stream>>>(xA, p8, Cc[1], ssrc, offs, agg_h, flags);
    k_gemm_mfma<<<GB, 256, 0, stream>>>(agg_h, wt2, Bb[1], uf3, xB, p8, NN, 1, flags);

    // ---- layer 3: 128 -> 128, relu ----
    k_agg128<<<NWB, 256, 0, stream>>>(xB, p8, Cc[2], ssrc, offs, agg_h, flags);
    k_gemm_mfma<<<GB, 256, 0, stream>>>(agg_h, wt3, Bb[2], nullptr, xA, nullptr, NN, 1, flags);

    // ---- layer 4: 128 -> 3 (transform-first; y4 bf16 + p fused) ----
    k_y4p<<<GB, 256, 0, stream>>>(xA, wt4, u4, y4h, p8);
    k_final_fast<<<NWB, 256, 0, stream>>>(y4h, p8, Cc[3], ssrc, offs, Bb[3], d_out, flags);
}